// Round 3
// baseline (1855.765 us; speedup 1.0000x reference)
//
#include <hip/hip_runtime.h>
#include <math.h>

// Problem constants
#define DIM   256
#define DIM4  64          // DIM/4 float4 per row
#define BN_EPS 1e-5f

// ---------------------------------------------------------------------------
// Degree / dinv
// ---------------------------------------------------------------------------
__global__ void k_deg_init(int* __restrict__ deg, int N) {
    int i = blockIdx.x * blockDim.x + threadIdx.x;
    if (i < N) deg[i] = 1;   // self-loop
}

__global__ void k_deg_count(const int* __restrict__ dst, int* __restrict__ deg, int E) {
    for (int e = blockIdx.x * blockDim.x + threadIdx.x; e < E; e += gridDim.x * blockDim.x) {
        atomicAdd(&deg[dst[e]], 1);
    }
}

__global__ void k_dinv(const int* __restrict__ deg, float* __restrict__ dinv, int N) {
    int i = blockIdx.x * blockDim.x + threadIdx.x;
    if (i < N) dinv[i] = rsqrtf((float)deg[i]);
}

// ---------------------------------------------------------------------------
// Exclusive scan of in-degree (deg-1) -> rowstart, cursor  (1024 elems/block)
// ---------------------------------------------------------------------------
__global__ void k_scan_partial(const int* __restrict__ deg, int* __restrict__ part, int N) {
    __shared__ int sh[256];
    int base = blockIdx.x * 1024 + threadIdx.x * 4;
    int s = 0;
#pragma unroll
    for (int q = 0; q < 4; ++q) {
        int i = base + q;
        if (i < N) s += deg[i] - 1;
    }
    sh[threadIdx.x] = s;
    __syncthreads();
    for (int off = 128; off > 0; off >>= 1) {
        if (threadIdx.x < off) sh[threadIdx.x] += sh[threadIdx.x + off];
        __syncthreads();
    }
    if (threadIdx.x == 0) part[blockIdx.x] = sh[0];
}

__global__ void k_scan_offsets(int* __restrict__ part, int* __restrict__ rowstart, int nb, int N) {
    // single thread; nb ~ 98
    int run = 0;
    for (int i = 0; i < nb; ++i) { int v = part[i]; part[i] = run; run += v; }
    rowstart[N] = run;   // == E
}

__global__ void k_scan_write(const int* __restrict__ deg, const int* __restrict__ part,
                             int* __restrict__ rowstart, int* __restrict__ cursor, int N) {
    __shared__ int sh[256];
    int base = blockIdx.x * 1024 + threadIdx.x * 4;
    int v[4]; int s = 0;
#pragma unroll
    for (int q = 0; q < 4; ++q) {
        int i = base + q;
        v[q] = (i < N) ? deg[i] - 1 : 0;
        s += v[q];
    }
    sh[threadIdx.x] = s;
    __syncthreads();
    if (threadIdx.x == 0) {
        int run = part[blockIdx.x];
        for (int t = 0; t < 256; ++t) { int x = sh[t]; sh[t] = run; run += x; }
    }
    __syncthreads();
    int run = sh[threadIdx.x];
#pragma unroll
    for (int q = 0; q < 4; ++q) {
        int i = base + q;
        if (i < N) { rowstart[i] = run; cursor[i] = run; run += v[q]; }
    }
}

__global__ void k_fill(const int* __restrict__ src, const int* __restrict__ dst,
                       int* __restrict__ cursor, int* __restrict__ col, int E) {
    for (int e = blockIdx.x * blockDim.x + threadIdx.x; e < E; e += gridDim.x * blockDim.x) {
        int d = dst[e];
        int p = atomicAdd(&cursor[d], 1);
        col[p] = src[e];
    }
}

// ---------------------------------------------------------------------------
// Aggregation: out[i] = dinv[i] * ( sum_j dinv[j]*x[j] + dinv[i]*x[i] )
// one wave (64 lanes) per node, lane = float4 column
// ---------------------------------------------------------------------------
__global__ __launch_bounds__(256) void k_agg(const float4* __restrict__ x,
                                             const float* __restrict__ dinv,
                                             const int* __restrict__ rowstart,
                                             const int* __restrict__ col,
                                             float4* __restrict__ out,
                                             float* __restrict__ rs,
                                             int N, int writeRs) {
    int wave = (blockIdx.x * blockDim.x + threadIdx.x) >> 6;
    int lane = threadIdx.x & 63;
    if (wave >= N) return;
    float di = dinv[wave];
    float4 xv = x[wave * DIM4 + lane];
    float ax = di * xv.x, ay = di * xv.y, az = di * xv.z, aw = di * xv.w;
    float sd = 0.f;
    int s = rowstart[wave], e = rowstart[wave + 1];
    int p = s;
    if (p < e) {
        int j = col[p]; float dj = dinv[j];
        for (++p; p < e; ++p) {
            int jn = col[p]; float djn = dinv[jn];      // prefetch next
            float4 v = x[j * DIM4 + lane];
            ax += dj * v.x; ay += dj * v.y; az += dj * v.z; aw += dj * v.w;
            sd += dj;
            j = jn; dj = djn;
        }
        float4 v = x[j * DIM4 + lane];
        ax += dj * v.x; ay += dj * v.y; az += dj * v.z; aw += dj * v.w;
        sd += dj;
    }
    float4 o; o.x = di * ax; o.y = di * ay; o.z = di * az; o.w = di * aw;
    out[wave * DIM4 + lane] = o;
    if (writeRs && lane == 0) rs[wave] = di * (sd + di);
}

// ---------------------------------------------------------------------------
// Weight collapse: Wc = W1 @ W2   ([256,512] @ [512,256]); cvec = b1 @ W2
// ---------------------------------------------------------------------------
__global__ void k_wc(const float* __restrict__ W1, const float* __restrict__ W2,
                     float* __restrict__ Wc) {
    int i = blockIdx.x, j = threadIdx.x;
    float acc = 0.f;
    for (int k = 0; k < 2 * DIM; ++k) acc += W1[i * 2 * DIM + k] * W2[k * DIM + j];
    Wc[i * DIM + j] = acc;
}

__global__ void k_cvec(const float* __restrict__ b1, const float* __restrict__ W2,
                       float* __restrict__ cvec) {
    int j = threadIdx.x;
    float acc = 0.f;
    for (int k = 0; k < 2 * DIM; ++k) acc += b1[k] * W2[k * DIM + j];
    cvec[j] = acc;
}

// ---------------------------------------------------------------------------
// GEMM: C = A[N,256] @ Wc[256,256] + rs[:,None]*cvec[None,:] + b2[None,:]
// BM=BN=64, BK=32, 256 threads, 4x4 micro-tile
// ---------------------------------------------------------------------------
#define BM 64
#define BN 64
#define BK 32
#define ALDS (BM + 4)   // stride 68 floats: 16B-aligned rows, spread banks

__global__ __launch_bounds__(256) void k_gemm(const float* __restrict__ A,
                                              const float* __restrict__ B,
                                              const float* __restrict__ rs,
                                              const float* __restrict__ cvec,
                                              const float* __restrict__ b2,
                                              float* __restrict__ C, int N) {
    __shared__ float As[BK][ALDS];
    __shared__ float Bs[BK][BN];
    int row0 = blockIdx.x * BM;
    int col0 = blockIdx.y * BN;
    int tid = threadIdx.x;
    int tm = (tid >> 4) << 2;    // 0..60
    int tn = (tid & 15) << 2;    // 0..60
    float acc[4][4] = {};

    for (int k0 = 0; k0 < DIM; k0 += BK) {
        // A tile: 64 rows x 32 cols -> transposed into As[k][m]
#pragma unroll
        for (int q = 0; q < 2; ++q) {
            int idx = tid + q * 256;          // 0..511
            int r = idx >> 3;                 // 8 float4 per row
            int c4 = idx & 7;
            float4 v;
            int grow = row0 + r;
            if (grow < N) v = reinterpret_cast<const float4*>(A)[grow * DIM4 + (k0 >> 2) + c4];
            else          v = make_float4(0.f, 0.f, 0.f, 0.f);
            int c = c4 << 2;
            As[c + 0][r] = v.x; As[c + 1][r] = v.y; As[c + 2][r] = v.z; As[c + 3][r] = v.w;
        }
        // B tile: 32 rows x 64 cols
#pragma unroll
        for (int q = 0; q < 2; ++q) {
            int idx = tid + q * 256;
            int r = idx >> 4;                 // 16 float4 per row
            int c4 = idx & 15;
            float4 v = reinterpret_cast<const float4*>(B)[(k0 + r) * DIM4 + (col0 >> 2) + c4];
            reinterpret_cast<float4*>(&Bs[r][0])[c4] = v;
        }
        __syncthreads();
#pragma unroll
        for (int k = 0; k < BK; ++k) {
            float a0 = As[k][tm], a1 = As[k][tm + 1], a2 = As[k][tm + 2], a3 = As[k][tm + 3];
            float b0 = Bs[k][tn], b1v = Bs[k][tn + 1], b2v = Bs[k][tn + 2], b3 = Bs[k][tn + 3];
            acc[0][0] += a0 * b0; acc[0][1] += a0 * b1v; acc[0][2] += a0 * b2v; acc[0][3] += a0 * b3;
            acc[1][0] += a1 * b0; acc[1][1] += a1 * b1v; acc[1][2] += a1 * b2v; acc[1][3] += a1 * b3;
            acc[2][0] += a2 * b0; acc[2][1] += a2 * b1v; acc[2][2] += a2 * b2v; acc[2][3] += a2 * b3;
            acc[3][0] += a3 * b0; acc[3][1] += a3 * b1v; acc[3][2] += a3 * b2v; acc[3][3] += a3 * b3;
        }
        __syncthreads();
    }

    float4 cv = reinterpret_cast<const float4*>(cvec)[(col0 + tn) >> 2];
    float4 bv = reinterpret_cast<const float4*>(b2)[(col0 + tn) >> 2];
#pragma unroll
    for (int i = 0; i < 4; ++i) {
        int r = row0 + tm + i;
        if (r < N) {
            float rv = rs[r];
            float4 o;
            o.x = acc[i][0] + rv * cv.x + bv.x;
            o.y = acc[i][1] + rv * cv.y + bv.y;
            o.z = acc[i][2] + rv * cv.z + bv.z;
            o.w = acc[i][3] + rv * cv.w + bv.w;
            reinterpret_cast<float4*>(C)[r * DIM4 + ((col0 + tn) >> 2)] = o;
        }
    }
}

// ---------------------------------------------------------------------------
// BatchNorm (training-mode, biased var) over axis 0
// ---------------------------------------------------------------------------
__global__ void k_bnzero(float* __restrict__ p) {
    p[threadIdx.x] = 0.f;   // 512 threads: sum[256] + sumsq[256]
}

__global__ __launch_bounds__(256) void k_bnstats(const float* __restrict__ h,
                                                 float* __restrict__ sum,
                                                 float* __restrict__ sq, int N) {
    int ch = threadIdx.x;
    float s = 0.f, ss = 0.f;
    for (int r = blockIdx.x; r < N; r += gridDim.x) {
        float v = h[r * DIM + ch];
        s += v; ss += v * v;
    }
    atomicAdd(&sum[ch], s);
    atomicAdd(&sq[ch], ss);
}

__global__ void k_bnfinal(const float* __restrict__ sum, const float* __restrict__ sq,
                          const float* __restrict__ gamma, const float* __restrict__ beta,
                          float* __restrict__ scale, float* __restrict__ shift, int N) {
    int ch = threadIdx.x;
    float invN = 1.0f / (float)N;
    float mean = sum[ch] * invN;
    float var = sq[ch] * invN - mean * mean;
    float inv = rsqrtf(var + BN_EPS);
    float sc = gamma[ch] * inv;
    scale[ch] = sc;
    shift[ch] = beta[ch] - mean * sc;
}

__global__ __launch_bounds__(256) void k_bnnorm(float4* __restrict__ out,
                                                const float4* __restrict__ scale,
                                                const float4* __restrict__ shift, int n4) {
    for (int i = blockIdx.x * blockDim.x + threadIdx.x; i < n4; i += gridDim.x * blockDim.x) {
        int j = i & (DIM4 - 1);
        float4 v = out[i];
        float4 sc = scale[j];
        float4 sh = shift[j];
        v.x = v.x * sc.x + sh.x;
        v.y = v.y * sc.y + sh.y;
        v.z = v.z * sc.z + sh.z;
        v.w = v.w * sc.w + sh.w;
        out[i] = v;
    }
}

// ---------------------------------------------------------------------------
extern "C" void kernel_launch(void* const* d_in, const int* in_sizes, int n_in,
                              void* d_out, int out_size, void* d_ws, size_t ws_size,
                              hipStream_t stream) {
    const int* ei        = (const int*)d_in[0];     // int32 per harness convention
    const float* emb     = (const float*)d_in[1];
    const float* W1      = (const float*)d_in[2];
    const float* b1      = (const float*)d_in[3];
    const float* W2      = (const float*)d_in[4];
    const float* b2      = (const float*)d_in[5];
    const float* gamma   = (const float*)d_in[6];
    const float* beta    = (const float*)d_in[7];

    const int E = in_sizes[0] / 2;
    const int N = in_sizes[1] / DIM;
    const int* src = ei;
    const int* dst = ei + E;

    // workspace carve-up (256B aligned)
    char* w = (char*)d_ws;
    size_t off = 0;
    auto alloc = [&](size_t bytes) -> void* {
        off = (off + 255) & ~(size_t)255;
        void* p = w + off;
        off += bytes;
        return p;
    };
    int*   deg      = (int*)  alloc((size_t)N * 4);
    float* dinv     = (float*)alloc((size_t)N * 4);
    int*   rowstart = (int*)  alloc((size_t)(N + 1) * 4);
    int*   cursor   = (int*)  alloc((size_t)N * 4);
    int*   part     = (int*)  alloc(1024);
    int*   csr_col  = (int*)  alloc((size_t)E * 4);
    float* rs       = (float*)alloc((size_t)N * 4);
    float* agg2     = (float*)alloc((size_t)N * DIM * 4);
    float* Wc       = (float*)alloc((size_t)DIM * DIM * 4);
    float* cvec     = (float*)alloc(DIM * 4);
    float* bnsum    = (float*)alloc(2 * DIM * 4);   // sum | sumsq
    float* bnscale  = (float*)alloc(2 * DIM * 4);   // scale | shift
    float* out      = (float*)d_out;                // also agg1 scratch

    const int nb1024 = (N + 1023) / 1024;

    // 1. degree + dinv
    k_deg_init<<<(N + 255) / 256, 256, 0, stream>>>(deg, N);
    k_deg_count<<<2048, 256, 0, stream>>>(dst, deg, E);
    k_dinv<<<(N + 255) / 256, 256, 0, stream>>>(deg, dinv, N);

    // 2. CSR build
    k_scan_partial<<<nb1024, 256, 0, stream>>>(deg, part, N);
    k_scan_offsets<<<1, 1, 0, stream>>>(part, rowstart, nb1024, N);
    k_scan_write<<<nb1024, 256, 0, stream>>>(deg, part, rowstart, cursor, N);
    k_fill<<<2048, 256, 0, stream>>>(src, dst, cursor, csr_col, E);

    // 3. agg1 = A @ x  -> d_out (scratch); also rs = A @ 1
    k_agg<<<(N + 3) / 4, 256, 0, stream>>>((const float4*)emb, dinv, rowstart, csr_col,
                                           (float4*)out, rs, N, 1);
    // 4. agg2 = A @ agg1 -> ws
    k_agg<<<(N + 3) / 4, 256, 0, stream>>>((const float4*)out, dinv, rowstart, csr_col,
                                           (float4*)agg2, rs, N, 0);

    // 5. weight collapse
    k_wc<<<DIM, DIM, 0, stream>>>(W1, W2, Wc);
    k_cvec<<<1, DIM, 0, stream>>>(b1, W2, cvec);

    // 6. h2 = agg2 @ Wc + rs⊗cvec + b2  -> d_out
    dim3 ggrid((N + BM - 1) / BM, DIM / BN);
    k_gemm<<<ggrid, 256, 0, stream>>>(agg2, Wc, rs, cvec, b2, out, N);

    // 7. BatchNorm
    k_bnzero<<<1, 512, 0, stream>>>(bnsum);
    k_bnstats<<<512, 256, 0, stream>>>(out, bnsum, bnsum + DIM, N);
    k_bnfinal<<<1, DIM, 0, stream>>>(bnsum, bnsum + DIM, gamma, beta,
                                     bnscale, bnscale + DIM, N);
    k_bnnorm<<<2048, 256, 0, stream>>>((float4*)out, (const float4*)bnscale,
                                       (const float4*)(bnscale + DIM), N * DIM4);
}

// Round 7
// 1414.635 us; speedup vs baseline: 1.3118x; 1.3118x over previous
//
#include <hip/hip_runtime.h>
#include <hip/hip_fp16.h>
#include <math.h>

// Problem constants
#define DIM   256
#define DIM4  64          // DIM/4 float4 per row
#define DIMH2 64          // DIM/4 halves-packed-as-uint2 per row (4 halves each)
#define BN_EPS 1e-5f

__device__ __forceinline__ unsigned h2u(__half2 h) { return __builtin_bit_cast(unsigned, h); }
__device__ __forceinline__ __half2 u2h(unsigned u) { return __builtin_bit_cast(__half2, u); }

// ---------------------------------------------------------------------------
// Degree / dinv
// ---------------------------------------------------------------------------
__global__ void k_deg_init(int* __restrict__ deg, int N) {
    int i = blockIdx.x * blockDim.x + threadIdx.x;
    if (i < N) deg[i] = 1;   // self-loop
}

__global__ void k_deg_count(const int* __restrict__ dst, int* __restrict__ deg, int E) {
    for (int e = blockIdx.x * blockDim.x + threadIdx.x; e < E; e += gridDim.x * blockDim.x) {
        atomicAdd(&deg[dst[e]], 1);
    }
}

__global__ void k_dinv(const int* __restrict__ deg, float* __restrict__ dinv, int N) {
    int i = blockIdx.x * blockDim.x + threadIdx.x;
    if (i < N) dinv[i] = rsqrtf((float)deg[i]);
}

// ---------------------------------------------------------------------------
// fp32 -> fp16 table conversion (4 floats -> 4 halves = 8B per thread-iter)
// ---------------------------------------------------------------------------
__global__ __launch_bounds__(256) void k_tohalf(const float4* __restrict__ in,
                                                uint2* __restrict__ outh, int n4) {
    for (int i = blockIdx.x * blockDim.x + threadIdx.x; i < n4; i += gridDim.x * blockDim.x) {
        float4 v = in[i];
        uint2 o;
        o.x = h2u(__halves2half2(__float2half_rn(v.x), __float2half_rn(v.y)));
        o.y = h2u(__halves2half2(__float2half_rn(v.z), __float2half_rn(v.w)));
        outh[i] = o;
    }
}

// ---------------------------------------------------------------------------
// Exclusive scan of in-degree (deg-1) -> rowstart, cursor  (1024 elems/block)
// ---------------------------------------------------------------------------
__global__ void k_scan_partial(const int* __restrict__ deg, int* __restrict__ part, int N) {
    __shared__ int sh[256];
    int base = blockIdx.x * 1024 + threadIdx.x * 4;
    int s = 0;
#pragma unroll
    for (int q = 0; q < 4; ++q) {
        int i = base + q;
        if (i < N) s += deg[i] - 1;
    }
    sh[threadIdx.x] = s;
    __syncthreads();
    for (int off = 128; off > 0; off >>= 1) {
        if (threadIdx.x < off) sh[threadIdx.x] += sh[threadIdx.x + off];
        __syncthreads();
    }
    if (threadIdx.x == 0) part[blockIdx.x] = sh[0];
}

__global__ void k_scan_offsets(int* __restrict__ part, int* __restrict__ rowstart, int nb, int N) {
    int run = 0;
    for (int i = 0; i < nb; ++i) { int v = part[i]; part[i] = run; run += v; }
    rowstart[N] = run;   // == E
}

__global__ void k_scan_write(const int* __restrict__ deg, const int* __restrict__ part,
                             int* __restrict__ rowstart, int* __restrict__ cursor, int N) {
    __shared__ int sh[256];
    int base = blockIdx.x * 1024 + threadIdx.x * 4;
    int v[4]; int s = 0;
#pragma unroll
    for (int q = 0; q < 4; ++q) {
        int i = base + q;
        v[q] = (i < N) ? deg[i] - 1 : 0;
        s += v[q];
    }
    sh[threadIdx.x] = s;
    __syncthreads();
    if (threadIdx.x == 0) {
        int run = part[blockIdx.x];
        for (int t = 0; t < 256; ++t) { int x = sh[t]; sh[t] = run; run += x; }
    }
    __syncthreads();
    int run = sh[threadIdx.x];
#pragma unroll
    for (int q = 0; q < 4; ++q) {
        int i = base + q;
        if (i < N) { rowstart[i] = run; cursor[i] = run; run += v[q]; }
    }
}

__global__ void k_fill(const int* __restrict__ src, const int* __restrict__ dst,
                       int* __restrict__ cursor, int* __restrict__ col, int E) {
    for (int e = blockIdx.x * blockDim.x + threadIdx.x; e < E; e += gridDim.x * blockDim.x) {
        int d = dst[e];
        int p = atomicAdd(&cursor[d], 1);
        col[p] = src[e];
    }
}

// ---------------------------------------------------------------------------
// Aggregation over fp16 table, fp32 accumulate.
// out[i] = dinv[i] * ( sum_j dinv[j]*x[j] + dinv[i]*x[i] )
// one wave per node; lane = 4-half (8B) column slice.
// Two variants: fp16 output (pass 1) and fp32 output (pass 2).
// ---------------------------------------------------------------------------
__global__ __launch_bounds__(256) void k_agg_h2h(const uint2* __restrict__ xh,
                                                 const float* __restrict__ dinv,
                                                 const int* __restrict__ rowstart,
                                                 const int* __restrict__ col,
                                                 uint2* __restrict__ outh,
                                                 float* __restrict__ rs, int N) {
    int wave = (blockIdx.x * blockDim.x + threadIdx.x) >> 6;
    int lane = threadIdx.x & 63;
    if (wave >= N) return;
    float di = dinv[wave];
    uint2 xraw = xh[(size_t)wave * DIMH2 + lane];
    float2 f0 = __half22float2(u2h(xraw.x));
    float2 f1 = __half22float2(u2h(xraw.y));
    float ax = di * f0.x, ay = di * f0.y, az = di * f1.x, aw = di * f1.y;
    float sd = 0.f;
    int p = rowstart[wave], e = rowstart[wave + 1];
    if (p < e) {
        int j = col[p]; float dj = dinv[j];
        for (++p; p < e; ++p) {
            int jn = col[p]; float djn = dinv[jn];      // prefetch next
            uint2 raw = xh[(size_t)j * DIMH2 + lane];
            float2 v0 = __half22float2(u2h(raw.x));
            float2 v1 = __half22float2(u2h(raw.y));
            ax += dj * v0.x; ay += dj * v0.y; az += dj * v1.x; aw += dj * v1.y;
            sd += dj;
            j = jn; dj = djn;
        }
        uint2 raw = xh[(size_t)j * DIMH2 + lane];
        float2 v0 = __half22float2(u2h(raw.x));
        float2 v1 = __half22float2(u2h(raw.y));
        ax += dj * v0.x; ay += dj * v0.y; az += dj * v1.x; aw += dj * v1.y;
        sd += dj;
    }
    uint2 o;
    o.x = h2u(__halves2half2(__float2half_rn(di * ax), __float2half_rn(di * ay)));
    o.y = h2u(__halves2half2(__float2half_rn(di * az), __float2half_rn(di * aw)));
    outh[(size_t)wave * DIMH2 + lane] = o;
    if (lane == 0) rs[wave] = di * (sd + di);
}

__global__ __launch_bounds__(256) void k_agg_h2f(const uint2* __restrict__ xh,
                                                 const float* __restrict__ dinv,
                                                 const int* __restrict__ rowstart,
                                                 const int* __restrict__ col,
                                                 float4* __restrict__ out, int N) {
    int wave = (blockIdx.x * blockDim.x + threadIdx.x) >> 6;
    int lane = threadIdx.x & 63;
    if (wave >= N) return;
    float di = dinv[wave];
    uint2 xraw = xh[(size_t)wave * DIMH2 + lane];
    float2 f0 = __half22float2(u2h(xraw.x));
    float2 f1 = __half22float2(u2h(xraw.y));
    float ax = di * f0.x, ay = di * f0.y, az = di * f1.x, aw = di * f1.y;
    int p = rowstart[wave], e = rowstart[wave + 1];
    if (p < e) {
        int j = col[p]; float dj = dinv[j];
        for (++p; p < e; ++p) {
            int jn = col[p]; float djn = dinv[jn];      // prefetch next
            uint2 raw = xh[(size_t)j * DIMH2 + lane];
            float2 v0 = __half22float2(u2h(raw.x));
            float2 v1 = __half22float2(u2h(raw.y));
            ax += dj * v0.x; ay += dj * v0.y; az += dj * v1.x; aw += dj * v1.y;
            j = jn; dj = djn;
        }
        uint2 raw = xh[(size_t)j * DIMH2 + lane];
        float2 v0 = __half22float2(u2h(raw.x));
        float2 v1 = __half22float2(u2h(raw.y));
        ax += dj * v0.x; ay += dj * v0.y; az += dj * v1.x; aw += dj * v1.y;
    }
    float4 o; o.x = di * ax; o.y = di * ay; o.z = di * az; o.w = di * aw;
    out[(size_t)wave * DIM4 + lane] = o;
}

// ---------------------------------------------------------------------------
// Weight collapse: Wc = W1 @ W2   ([256,512] @ [512,256]); cvec = b1 @ W2
// ---------------------------------------------------------------------------
__global__ void k_wc(const float* __restrict__ W1, const float* __restrict__ W2,
                     float* __restrict__ Wc) {
    int i = blockIdx.x, j = threadIdx.x;
    float acc = 0.f;
    for (int k = 0; k < 2 * DIM; ++k) acc += W1[i * 2 * DIM + k] * W2[k * DIM + j];
    Wc[i * DIM + j] = acc;
}

__global__ void k_cvec(const float* __restrict__ b1, const float* __restrict__ W2,
                       float* __restrict__ cvec) {
    int j = threadIdx.x;
    float acc = 0.f;
    for (int k = 0; k < 2 * DIM; ++k) acc += b1[k] * W2[k * DIM + j];
    cvec[j] = acc;
}

// ---------------------------------------------------------------------------
// GEMM: C = A[N,256] @ Wc[256,256] + rs[:,None]*cvec[None,:] + b2[None,:]
// BM=BN=64, BK=32, 256 threads, 4x4 micro-tile
// ---------------------------------------------------------------------------
#define BM 64
#define BN 64
#define BK 32
#define ALDS (BM + 4)   // stride 68 floats: 16B-aligned rows, spread banks

__global__ __launch_bounds__(256) void k_gemm(const float* __restrict__ A,
                                              const float* __restrict__ B,
                                              const float* __restrict__ rs,
                                              const float* __restrict__ cvec,
                                              const float* __restrict__ b2,
                                              float* __restrict__ C, int N) {
    __shared__ float As[BK][ALDS];
    __shared__ float Bs[BK][BN];
    int row0 = blockIdx.x * BM;
    int col0 = blockIdx.y * BN;
    int tid = threadIdx.x;
    int tm = (tid >> 4) << 2;    // 0..60
    int tn = (tid & 15) << 2;    // 0..60
    float acc[4][4] = {};

    for (int k0 = 0; k0 < DIM; k0 += BK) {
        // A tile: 64 rows x 32 cols -> transposed into As[k][m]
#pragma unroll
        for (int q = 0; q < 2; ++q) {
            int idx = tid + q * 256;          // 0..511
            int r = idx >> 3;                 // 8 float4 per row
            int c4 = idx & 7;
            float4 v;
            int grow = row0 + r;
            if (grow < N) v = reinterpret_cast<const float4*>(A)[grow * DIM4 + (k0 >> 2) + c4];
            else          v = make_float4(0.f, 0.f, 0.f, 0.f);
            int c = c4 << 2;
            As[c + 0][r] = v.x; As[c + 1][r] = v.y; As[c + 2][r] = v.z; As[c + 3][r] = v.w;
        }
        // B tile: 32 rows x 64 cols
#pragma unroll
        for (int q = 0; q < 2; ++q) {
            int idx = tid + q * 256;
            int r = idx >> 4;                 // 16 float4 per row
            int c4 = idx & 15;
            float4 v = reinterpret_cast<const float4*>(B)[(k0 + r) * DIM4 + (col0 >> 2) + c4];
            reinterpret_cast<float4*>(&Bs[r][0])[c4] = v;
        }
        __syncthreads();
#pragma unroll
        for (int k = 0; k < BK; ++k) {
            float a0 = As[k][tm], a1 = As[k][tm + 1], a2 = As[k][tm + 2], a3 = As[k][tm + 3];
            float b0 = Bs[k][tn], b1v = Bs[k][tn + 1], b2v = Bs[k][tn + 2], b3 = Bs[k][tn + 3];
            acc[0][0] += a0 * b0; acc[0][1] += a0 * b1v; acc[0][2] += a0 * b2v; acc[0][3] += a0 * b3;
            acc[1][0] += a1 * b0; acc[1][1] += a1 * b1v; acc[1][2] += a1 * b2v; acc[1][3] += a1 * b3;
            acc[2][0] += a2 * b0; acc[2][1] += a2 * b1v; acc[2][2] += a2 * b2v; acc[2][3] += a2 * b3;
            acc[3][0] += a3 * b0; acc[3][1] += a3 * b1v; acc[3][2] += a3 * b2v; acc[3][3] += a3 * b3;
        }
        __syncthreads();
    }

    float4 cv = reinterpret_cast<const float4*>(cvec)[(col0 + tn) >> 2];
    float4 bv = reinterpret_cast<const float4*>(b2)[(col0 + tn) >> 2];
#pragma unroll
    for (int i = 0; i < 4; ++i) {
        int r = row0 + tm + i;
        if (r < N) {
            float rv = rs[r];
            float4 o;
            o.x = acc[i][0] + rv * cv.x + bv.x;
            o.y = acc[i][1] + rv * cv.y + bv.y;
            o.z = acc[i][2] + rv * cv.z + bv.z;
            o.w = acc[i][3] + rv * cv.w + bv.w;
            reinterpret_cast<float4*>(C)[r * DIM4 + ((col0 + tn) >> 2)] = o;
        }
    }
}

// ---------------------------------------------------------------------------
// BatchNorm (training-mode, biased var) over axis 0
// ---------------------------------------------------------------------------
__global__ void k_bnzero(float* __restrict__ p) {
    p[threadIdx.x] = 0.f;   // 512 threads: sum[256] + sumsq[256]
}

__global__ __launch_bounds__(256) void k_bnstats(const float* __restrict__ h,
                                                 float* __restrict__ sum,
                                                 float* __restrict__ sq, int N) {
    int ch = threadIdx.x;
    float s = 0.f, ss = 0.f;
    for (int r = blockIdx.x; r < N; r += gridDim.x) {
        float v = h[r * DIM + ch];
        s += v; ss += v * v;
    }
    atomicAdd(&sum[ch], s);
    atomicAdd(&sq[ch], ss);
}

__global__ void k_bnfinal(const float* __restrict__ sum, const float* __restrict__ sq,
                          const float* __restrict__ gamma, const float* __restrict__ beta,
                          float* __restrict__ scale, float* __restrict__ shift, int N) {
    int ch = threadIdx.x;
    float invN = 1.0f / (float)N;
    float mean = sum[ch] * invN;
    float var = sq[ch] * invN - mean * mean;
    float inv = rsqrtf(var + BN_EPS);
    float sc = gamma[ch] * inv;
    scale[ch] = sc;
    shift[ch] = beta[ch] - mean * sc;
}

__global__ __launch_bounds__(256) void k_bnnorm(float4* __restrict__ out,
                                                const float4* __restrict__ scale,
                                                const float4* __restrict__ shift, int n4) {
    for (int i = blockIdx.x * blockDim.x + threadIdx.x; i < n4; i += gridDim.x * blockDim.x) {
        int j = i & (DIM4 - 1);
        float4 v = out[i];
        float4 sc = scale[j];
        float4 sh = shift[j];
        v.x = v.x * sc.x + sh.x;
        v.y = v.y * sc.y + sh.y;
        v.z = v.z * sc.z + sh.z;
        v.w = v.w * sc.w + sh.w;
        out[i] = v;
    }
}

// ---------------------------------------------------------------------------
extern "C" void kernel_launch(void* const* d_in, const int* in_sizes, int n_in,
                              void* d_out, int out_size, void* d_ws, size_t ws_size,
                              hipStream_t stream) {
    const int* ei        = (const int*)d_in[0];     // int32 per harness convention
    const float* emb     = (const float*)d_in[1];
    const float* W1      = (const float*)d_in[2];
    const float* b1      = (const float*)d_in[3];
    const float* W2      = (const float*)d_in[4];
    const float* b2      = (const float*)d_in[5];
    const float* gamma   = (const float*)d_in[6];
    const float* beta    = (const float*)d_in[7];

    const int E = in_sizes[0] / 2;
    const int N = in_sizes[1] / DIM;
    const int* src = ei;
    const int* dst = ei + E;

    // workspace carve-up (256B aligned) — keeps footprint ~118MB as in R3
    char* w = (char*)d_ws;
    size_t off = 0;
    auto alloc = [&](size_t bytes) -> void* {
        off = (off + 255) & ~(size_t)255;
        void* p = w + off;
        off += bytes;
        return p;
    };
    int*   deg      = (int*)  alloc((size_t)N * 4);
    float* dinv     = (float*)alloc((size_t)N * 4);
    int*   rowstart = (int*)  alloc((size_t)(N + 1) * 4);
    int*   cursor   = (int*)  alloc((size_t)N * 4);
    int*   part     = (int*)  alloc(1024);
    int*   csr_col  = (int*)  alloc((size_t)E * 4);
    float* rs       = (float*)alloc((size_t)N * 4);
    float* agg2     = (float*)alloc((size_t)N * DIM * 4);
    float* Wc       = (float*)alloc((size_t)DIM * DIM * 4);
    float* cvec     = (float*)alloc(DIM * 4);
    float* bnsum    = (float*)alloc(2 * DIM * 4);   // sum | sumsq
    float* bnscale  = (float*)alloc(2 * DIM * 4);   // scale | shift

    // fp16 tables alias d_out (dead until the GEMM writes it):
    //   [0, N*DIM*2)        xh    = fp16(emb)
    //   [N*DIM*2, N*DIM*4)  agg1h = fp16(A @ emb)
    uint2* xh    = (uint2*)d_out;
    uint2* agg1h = (uint2*)((char*)d_out + (size_t)N * DIM * 2);
    float* out   = (float*)d_out;

    const int nb1024 = (N + 1023) / 1024;

    // 1. degree + dinv
    k_deg_init<<<(N + 255) / 256, 256, 0, stream>>>(deg, N);
    k_deg_count<<<2048, 256, 0, stream>>>(dst, deg, E);
    k_dinv<<<(N + 255) / 256, 256, 0, stream>>>(deg, dinv, N);

    // 2. fp16 gather table of emb
    k_tohalf<<<2048, 256, 0, stream>>>((const float4*)emb, xh, N * DIM4);

    // 3. CSR build
    k_scan_partial<<<nb1024, 256, 0, stream>>>(deg, part, N);
    k_scan_offsets<<<1, 1, 0, stream>>>(part, rowstart, nb1024, N);
    k_scan_write<<<nb1024, 256, 0, stream>>>(deg, part, rowstart, cursor, N);
    k_fill<<<2048, 256, 0, stream>>>(src, dst, cursor, csr_col, E);

    // 4. agg1h = fp16(A @ x); rs = A @ 1
    k_agg_h2h<<<(N + 3) / 4, 256, 0, stream>>>(xh, dinv, rowstart, csr_col, agg1h, rs, N);
    // 5. agg2 = A @ agg1   (fp32 out for GEMM)
    k_agg_h2f<<<(N + 3) / 4, 256, 0, stream>>>(agg1h, dinv, rowstart, csr_col,
                                               (float4*)agg2, N);

    // 6. weight collapse
    k_wc<<<DIM, DIM, 0, stream>>>(W1, W2, Wc);
    k_cvec<<<1, DIM, 0, stream>>>(b1, W2, cvec);

    // 7. h2 = agg2 @ Wc + rs⊗cvec + b2  -> d_out (overwrites dead fp16 tables)
    dim3 ggrid((N + BM - 1) / BM, DIM / BN);
    k_gemm<<<ggrid, 256, 0, stream>>>(agg2, Wc, rs, cvec, b2, out, N);

    // 8. BatchNorm
    k_bnzero<<<1, 512, 0, stream>>>(bnsum);
    k_bnstats<<<512, 256, 0, stream>>>(out, bnsum, bnsum + DIM, N);
    k_bnfinal<<<1, DIM, 0, stream>>>(bnsum, bnsum + DIM, gamma, beta,
                                     bnscale, bnscale + DIM, N);
    k_bnnorm<<<2048, 256, 0, stream>>>((float4*)out, (const float4*)bnscale,
                                       (const float4*)(bnscale + DIM), N * DIM4);
}

// Round 9
// 1280.514 us; speedup vs baseline: 1.4492x; 1.1047x over previous
//
#include <hip/hip_runtime.h>
#include <hip/hip_fp16.h>
#include <math.h>

// Problem constants
#define DIM   256
#define DIM4  64          // DIM/4 float4 per row
#define DIMH2 64          // DIM/4 halves-packed-as-uint2 per row (4 halves each)
#define BN_EPS 1e-5f

typedef __attribute__((ext_vector_type(8))) _Float16 half8;
typedef __attribute__((ext_vector_type(4))) float f32x4;

__device__ __forceinline__ unsigned h2u(__half2 h) { return __builtin_bit_cast(unsigned, h); }
__device__ __forceinline__ __half2 u2h(unsigned u) { return __builtin_bit_cast(__half2, u); }

// ---------------------------------------------------------------------------
// Degree / dinv
// ---------------------------------------------------------------------------
__global__ void k_deg_init(int* __restrict__ deg, int N) {
    int i = blockIdx.x * blockDim.x + threadIdx.x;
    if (i < N) deg[i] = 1;   // self-loop
}

__global__ void k_deg_count(const int* __restrict__ dst, int* __restrict__ deg, int E) {
    for (int e = blockIdx.x * blockDim.x + threadIdx.x; e < E; e += gridDim.x * blockDim.x) {
        atomicAdd(&deg[dst[e]], 1);
    }
}

__global__ void k_dinv(const int* __restrict__ deg, float* __restrict__ dinv, int N) {
    int i = blockIdx.x * blockDim.x + threadIdx.x;
    if (i < N) dinv[i] = rsqrtf((float)deg[i]);
}

// ---------------------------------------------------------------------------
// fp32 -> fp16 table conversion (4 floats -> 4 halves = 8B per thread-iter)
// ---------------------------------------------------------------------------
__global__ __launch_bounds__(256) void k_tohalf(const float4* __restrict__ in,
                                                uint2* __restrict__ outh, int n4) {
    for (int i = blockIdx.x * blockDim.x + threadIdx.x; i < n4; i += gridDim.x * blockDim.x) {
        float4 v = in[i];
        uint2 o;
        o.x = h2u(__halves2half2(__float2half_rn(v.x), __float2half_rn(v.y)));
        o.y = h2u(__halves2half2(__float2half_rn(v.z), __float2half_rn(v.w)));
        outh[i] = o;
    }
}

// ---------------------------------------------------------------------------
// Exclusive scan of in-degree (deg-1) -> rowstart, cursor  (1024 elems/block)
// ---------------------------------------------------------------------------
__global__ void k_scan_partial(const int* __restrict__ deg, int* __restrict__ part, int N) {
    __shared__ int sh[256];
    int base = blockIdx.x * 1024 + threadIdx.x * 4;
    int s = 0;
#pragma unroll
    for (int q = 0; q < 4; ++q) {
        int i = base + q;
        if (i < N) s += deg[i] - 1;
    }
    sh[threadIdx.x] = s;
    __syncthreads();
    for (int off = 128; off > 0; off >>= 1) {
        if (threadIdx.x < off) sh[threadIdx.x] += sh[threadIdx.x + off];
        __syncthreads();
    }
    if (threadIdx.x == 0) part[blockIdx.x] = sh[0];
}

__global__ void k_scan_offsets(int* __restrict__ part, int* __restrict__ rowstart, int nb, int N) {
    int run = 0;
    for (int i = 0; i < nb; ++i) { int v = part[i]; part[i] = run; run += v; }
    rowstart[N] = run;   // == E
}

__global__ void k_scan_write(const int* __restrict__ deg, const int* __restrict__ part,
                             int* __restrict__ rowstart, int* __restrict__ cursor, int N) {
    __shared__ int sh[256];
    int base = blockIdx.x * 1024 + threadIdx.x * 4;
    int v[4]; int s = 0;
#pragma unroll
    for (int q = 0; q < 4; ++q) {
        int i = base + q;
        v[q] = (i < N) ? deg[i] - 1 : 0;
        s += v[q];
    }
    sh[threadIdx.x] = s;
    __syncthreads();
    if (threadIdx.x == 0) {
        int run = part[blockIdx.x];
        for (int t = 0; t < 256; ++t) { int x = sh[t]; sh[t] = run; run += x; }
    }
    __syncthreads();
    int run = sh[threadIdx.x];
#pragma unroll
    for (int q = 0; q < 4; ++q) {
        int i = base + q;
        if (i < N) { rowstart[i] = run; cursor[i] = run; run += v[q]; }
    }
}

__global__ void k_fill(const int* __restrict__ src, const int* __restrict__ dst,
                       int* __restrict__ cursor, int* __restrict__ col, int E) {
    for (int e = blockIdx.x * blockDim.x + threadIdx.x; e < E; e += gridDim.x * blockDim.x) {
        int d = dst[e];
        int p = atomicAdd(&cursor[d], 1);
        col[p] = src[e];
    }
}

// ---------------------------------------------------------------------------
// Aggregation over fp16 table, fp32 accumulate.
// out[i] = dinv[i] * ( sum_j dinv[j]*x[j] + dinv[i]*x[i] )
// one wave per node; lane = 4-half (8B) column slice. fp16 output.
// ---------------------------------------------------------------------------
__global__ __launch_bounds__(256) void k_agg_h2h(const uint2* __restrict__ xh,
                                                 const float* __restrict__ dinv,
                                                 const int* __restrict__ rowstart,
                                                 const int* __restrict__ col,
                                                 uint2* __restrict__ outh,
                                                 float* __restrict__ rs, int N, int writeRs) {
    int wave = (blockIdx.x * blockDim.x + threadIdx.x) >> 6;
    int lane = threadIdx.x & 63;
    if (wave >= N) return;
    float di = dinv[wave];
    uint2 xraw = xh[(size_t)wave * DIMH2 + lane];
    float2 f0 = __half22float2(u2h(xraw.x));
    float2 f1 = __half22float2(u2h(xraw.y));
    float ax = di * f0.x, ay = di * f0.y, az = di * f1.x, aw = di * f1.y;
    float sd = 0.f;
    int p = rowstart[wave], e = rowstart[wave + 1];
    if (p < e) {
        int j = col[p]; float dj = dinv[j];
        for (++p; p < e; ++p) {
            int jn = col[p]; float djn = dinv[jn];      // prefetch next
            uint2 raw = xh[(size_t)j * DIMH2 + lane];
            float2 v0 = __half22float2(u2h(raw.x));
            float2 v1 = __half22float2(u2h(raw.y));
            ax += dj * v0.x; ay += dj * v0.y; az += dj * v1.x; aw += dj * v1.y;
            sd += dj;
            j = jn; dj = djn;
        }
        uint2 raw = xh[(size_t)j * DIMH2 + lane];
        float2 v0 = __half22float2(u2h(raw.x));
        float2 v1 = __half22float2(u2h(raw.y));
        ax += dj * v0.x; ay += dj * v0.y; az += dj * v1.x; aw += dj * v1.y;
        sd += dj;
    }
    uint2 o;
    o.x = h2u(__halves2half2(__float2half_rn(di * ax), __float2half_rn(di * ay)));
    o.y = h2u(__halves2half2(__float2half_rn(di * az), __float2half_rn(di * aw)));
    outh[(size_t)wave * DIMH2 + lane] = o;
    if (writeRs && lane == 0) rs[wave] = di * (sd + di);
}

// ---------------------------------------------------------------------------
// Weight collapse: WcT[j][i] = fp16( (W1 @ W2)[i][j] ); cvec = b1 @ W2 (fp32)
// ---------------------------------------------------------------------------
__global__ void k_wct(const float* __restrict__ W1, const float* __restrict__ W2,
                      _Float16* __restrict__ WcT) {
    int i = blockIdx.x, j = threadIdx.x;
    float acc = 0.f;
    for (int k = 0; k < 2 * DIM; ++k) acc += W1[i * 2 * DIM + k] * W2[k * DIM + j];
    WcT[(size_t)j * DIM + i] = (_Float16)acc;
}

__global__ void k_cvec(const float* __restrict__ b1, const float* __restrict__ W2,
                       float* __restrict__ cvec) {
    int j = threadIdx.x;
    float acc = 0.f;
    for (int k = 0; k < 2 * DIM; ++k) acc += b1[k] * W2[k * DIM + j];
    cvec[j] = acc;
}

// ---------------------------------------------------------------------------
// MFMA GEMM: C[N,256] = Ah[N,256] @ Wc + rs⊗cvec + b2   (fp16 in, fp32 out)
// B supplied transposed (WcT[col][k]) so both operands stage as [row][k].
// Block 256 thr = 4 waves (2x2), tile 128x128, wave tile 64x64 = 4x4 frags
// of v_mfma_f32_16x16x32_f16. K loop: 8 steps of 32.
// Fragment maps (gfx950 16x16x32): A/B lane l: row|col = l%16, k=(l/16)*8+j.
// C/D lane l reg r: col = l&15, row = (l>>4)*4 + r   [learn_hip m89].
// ---------------------------------------------------------------------------
#define GBM 128
#define GBN 128
#define ASTR 40   // halves; 32 + 8 pad → 80B row stride, 16B aligned, 2-way banks

__global__ __launch_bounds__(256) void k_gemm_mfma(const _Float16* __restrict__ Ah,
                                                   const _Float16* __restrict__ BTh,
                                                   const float* __restrict__ rs,
                                                   const float* __restrict__ cvec,
                                                   const float* __restrict__ b2,
                                                   float* __restrict__ C, int N) {
    __shared__ _Float16 As[GBM][ASTR];
    __shared__ _Float16 Bs[GBN][ASTR];
    int tid  = threadIdx.x;
    int row0 = blockIdx.x * GBM;
    int col0 = blockIdx.y * GBN;
    int w    = tid >> 6;
    int lane = tid & 63;
    int wr   = (w >> 1) * 64;    // wave row offset in tile
    int wc   = (w & 1) * 64;     // wave col offset in tile
    int lr   = lane & 15;
    int kg   = lane >> 4;        // 0..3

    f32x4 acc[4][4];
#pragma unroll
    for (int i = 0; i < 4; ++i)
#pragma unroll
        for (int j = 0; j < 4; ++j) acc[i][j] = (f32x4)0.f;

    int sr = tid >> 2;           // 0..63 (two rows per thread: sr, sr+64)
    int sc = (tid & 3) * 8;      // half offset within 32-k row

    for (int k0 = 0; k0 < DIM; k0 += 32) {
        __syncthreads();
#pragma unroll
        for (int q = 0; q < 2; ++q) {
            int r  = sr + q * 64;
            int gr = row0 + r;
            half8 av = (half8)(_Float16)0.f;
            if (gr < N)
                av = *reinterpret_cast<const half8*>(&Ah[(size_t)gr * DIM + k0 + sc]);
            *reinterpret_cast<half8*>(&As[r][sc]) = av;
            half8 bv = *reinterpret_cast<const half8*>(&BTh[(size_t)(col0 + r) * DIM + k0 + sc]);
            *reinterpret_cast<half8*>(&Bs[r][sc]) = bv;
        }
        __syncthreads();

        half8 af[4], bf[4];
#pragma unroll
        for (int mm = 0; mm < 4; ++mm)
            af[mm] = *reinterpret_cast<const half8*>(&As[wr + mm * 16 + lr][kg * 8]);
#pragma unroll
        for (int nn = 0; nn < 4; ++nn)
            bf[nn] = *reinterpret_cast<const half8*>(&Bs[wc + nn * 16 + lr][kg * 8]);
#pragma unroll
        for (int mm = 0; mm < 4; ++mm)
#pragma unroll
            for (int nn = 0; nn < 4; ++nn)
                acc[mm][nn] = __builtin_amdgcn_mfma_f32_16x16x32_f16(af[mm], bf[nn],
                                                                     acc[mm][nn], 0, 0, 0);
    }

#pragma unroll
    for (int mm = 0; mm < 4; ++mm) {
        int rbase = row0 + wr + mm * 16 + kg * 4;
#pragma unroll
        for (int reg = 0; reg < 4; ++reg) {
            int r = rbase + reg;
            if (r < N) {
                float rv = rs[r];
#pragma unroll
                for (int nn = 0; nn < 4; ++nn) {
                    int c = col0 + wc + nn * 16 + lr;
                    C[(size_t)r * DIM + c] = acc[mm][nn][reg] + rv * cvec[c] + b2[c];
                }
            }
        }
    }
}

// ---------------------------------------------------------------------------
// BatchNorm (training-mode, biased var) over axis 0
// ---------------------------------------------------------------------------
__global__ void k_bnzero(float* __restrict__ p) {
    p[threadIdx.x] = 0.f;   // 512 threads: sum[256] + sumsq[256]
}

__global__ __launch_bounds__(256) void k_bnstats(const float* __restrict__ h,
                                                 float* __restrict__ sum,
                                                 float* __restrict__ sq, int N) {
    int ch = threadIdx.x;
    float s = 0.f, ss = 0.f;
    for (int r = blockIdx.x; r < N; r += gridDim.x) {
        float v = h[r * DIM + ch];
        s += v; ss += v * v;
    }
    atomicAdd(&sum[ch], s);
    atomicAdd(&sq[ch], ss);
}

__global__ void k_bnfinal(const float* __restrict__ sum, const float* __restrict__ sq,
                          const float* __restrict__ gamma, const float* __restrict__ beta,
                          float* __restrict__ scale, float* __restrict__ shift, int N) {
    int ch = threadIdx.x;
    float invN = 1.0f / (float)N;
    float mean = sum[ch] * invN;
    float var = sq[ch] * invN - mean * mean;
    float inv = rsqrtf(var + BN_EPS);
    float sc = gamma[ch] * inv;
    scale[ch] = sc;
    shift[ch] = beta[ch] - mean * sc;
}

__global__ __launch_bounds__(256) void k_bnnorm(float4* __restrict__ out,
                                                const float4* __restrict__ scale,
                                                const float4* __restrict__ shift, int n4) {
    for (int i = blockIdx.x * blockDim.x + threadIdx.x; i < n4; i += gridDim.x * blockDim.x) {
        int j = i & (DIM4 - 1);
        float4 v = out[i];
        float4 sc = scale[j];
        float4 sh = shift[j];
        v.x = v.x * sc.x + sh.x;
        v.y = v.y * sc.y + sh.y;
        v.z = v.z * sc.z + sh.z;
        v.w = v.w * sc.w + sh.w;
        out[i] = v;
    }
}

// ---------------------------------------------------------------------------
extern "C" void kernel_launch(void* const* d_in, const int* in_sizes, int n_in,
                              void* d_out, int out_size, void* d_ws, size_t ws_size,
                              hipStream_t stream) {
    const int* ei        = (const int*)d_in[0];     // int32 per harness convention
    const float* emb     = (const float*)d_in[1];
    const float* W1      = (const float*)d_in[2];
    const float* b1      = (const float*)d_in[3];
    const float* W2      = (const float*)d_in[4];
    const float* b2      = (const float*)d_in[5];
    const float* gamma   = (const float*)d_in[6];
    const float* beta    = (const float*)d_in[7];

    const int E = in_sizes[0] / 2;
    const int N = in_sizes[1] / DIM;
    const int* src = ei;
    const int* dst = ei + E;

    // workspace carve-up (256B aligned) — ~67MB, below proven ~118MB budget
    char* w = (char*)d_ws;
    size_t off = 0;
    auto alloc = [&](size_t bytes) -> void* {
        off = (off + 255) & ~(size_t)255;
        void* p = w + off;
        off += bytes;
        return p;
    };
    int*      deg      = (int*)     alloc((size_t)N * 4);
    float*    dinv     = (float*)   alloc((size_t)N * 4);
    int*      rowstart = (int*)     alloc((size_t)(N + 1) * 4);
    int*      cursor   = (int*)     alloc((size_t)N * 4);
    int*      part     = (int*)     alloc(1024);
    int*      csr_col  = (int*)     alloc((size_t)E * 4);
    float*    rs       = (float*)   alloc((size_t)N * 4);
    uint2*    agg2h    = (uint2*)   alloc((size_t)N * DIM * 2);   // fp16 [N,256]
    _Float16* WcTh     = (_Float16*)alloc((size_t)DIM * DIM * 2); // fp16 Wc^T
    float*    cvec     = (float*)   alloc(DIM * 4);
    float*    bnsum    = (float*)   alloc(2 * DIM * 4);   // sum | sumsq
    float*    bnscale  = (float*)   alloc(2 * DIM * 4);   // scale | shift

    // fp16 tables alias d_out (dead until the GEMM writes it):
    //   [0, N*DIM*2)        xh    = fp16(emb)
    //   [N*DIM*2, N*DIM*4)  agg1h = fp16(A @ emb)
    uint2* xh    = (uint2*)d_out;
    uint2* agg1h = (uint2*)((char*)d_out + (size_t)N * DIM * 2);
    float* out   = (float*)d_out;

    const int nb1024 = (N + 1023) / 1024;

    // 1. degree + dinv
    k_deg_init<<<(N + 255) / 256, 256, 0, stream>>>(deg, N);
    k_deg_count<<<2048, 256, 0, stream>>>(dst, deg, E);
    k_dinv<<<(N + 255) / 256, 256, 0, stream>>>(deg, dinv, N);

    // 2. fp16 gather table of emb
    k_tohalf<<<2048, 256, 0, stream>>>((const float4*)emb, xh, N * DIM4);

    // 3. CSR build
    k_scan_partial<<<nb1024, 256, 0, stream>>>(deg, part, N);
    k_scan_offsets<<<1, 1, 0, stream>>>(part, rowstart, nb1024, N);
    k_scan_write<<<nb1024, 256, 0, stream>>>(deg, part, rowstart, cursor, N);
    k_fill<<<2048, 256, 0, stream>>>(src, dst, cursor, csr_col, E);

    // 4. agg1h = fp16(A @ x); rs = A @ 1
    k_agg_h2h<<<(N + 3) / 4, 256, 0, stream>>>(xh, dinv, rowstart, csr_col, agg1h, rs, N, 1);
    // 5. agg2h = fp16(A @ agg1)
    k_agg_h2h<<<(N + 3) / 4, 256, 0, stream>>>(agg1h, dinv, rowstart, csr_col, agg2h, rs, N, 0);

    // 6. weight collapse (fp16 transposed for MFMA B-operand)
    k_wct<<<DIM, DIM, 0, stream>>>(W1, W2, WcTh);
    k_cvec<<<1, DIM, 0, stream>>>(b1, W2, cvec);

    // 7. h2 = agg2 @ Wc + rs⊗cvec + b2  -> d_out (overwrites dead fp16 tables)
    dim3 ggrid((N + GBM - 1) / GBM, DIM / GBN);
    k_gemm_mfma<<<ggrid, 256, 0, stream>>>((const _Float16*)agg2h, WcTh, rs, cvec, b2, out, N);

    // 8. BatchNorm
    k_bnzero<<<1, 512, 0, stream>>>(bnsum);
    k_bnstats<<<512, 256, 0, stream>>>(out, bnsum, bnsum + DIM, N);
    k_bnfinal<<<1, DIM, 0, stream>>>(bnsum, bnsum + DIM, gamma, beta,
                                     bnscale, bnscale + DIM, N);
    k_bnnorm<<<2048, 256, 0, stream>>>((float4*)out, (const float4*)bnscale,
                                       (const float4*)(bnscale + DIM), N * DIM4);
}

// Round 10
// 1090.518 us; speedup vs baseline: 1.7017x; 1.1742x over previous
//
#include <hip/hip_runtime.h>
#include <hip/hip_fp16.h>
#include <math.h>

// Problem constants
#define DIM   256
#define DIM4  64          // DIM/4 float4 per row
#define DIMH2 64          // DIM/4 halves-packed-as-uint2 per row (4 halves each)
#define BN_EPS 1e-5f

// Bucketed CSR-fill parameters
#define NPB      256      // nodes per bucket (pow2: bucket = dst >> 8)
#define MAXBUCK  512      // static LDS bound on bucket count (need 391)
#define CAP      13312    // per-bucket LDS edge capacity (avg 8192, +6 sigma ~8.7K)

typedef __attribute__((ext_vector_type(8))) _Float16 half8;
typedef __attribute__((ext_vector_type(4))) float f32x4;

__device__ __forceinline__ unsigned h2u(__half2 h) { return __builtin_bit_cast(unsigned, h); }
__device__ __forceinline__ __half2 u2h(unsigned u) { return __builtin_bit_cast(__half2, u); }

// ---------------------------------------------------------------------------
// Degree / dinv
// ---------------------------------------------------------------------------
__global__ void k_deg_init(int* __restrict__ deg, int N) {
    int i = blockIdx.x * blockDim.x + threadIdx.x;
    if (i < N) deg[i] = 1;   // self-loop
}

__global__ void k_deg_count(const int* __restrict__ dst, int* __restrict__ deg, int E) {
    for (int e = blockIdx.x * blockDim.x + threadIdx.x; e < E; e += gridDim.x * blockDim.x) {
        atomicAdd(&deg[dst[e]], 1);
    }
}

__global__ void k_dinv(const int* __restrict__ deg, float* __restrict__ dinv, int N) {
    int i = blockIdx.x * blockDim.x + threadIdx.x;
    if (i < N) dinv[i] = rsqrtf((float)deg[i]);
}

// ---------------------------------------------------------------------------
// fp32 -> fp16 table conversion (4 floats -> 4 halves = 8B per thread-iter)
// ---------------------------------------------------------------------------
__global__ __launch_bounds__(256) void k_tohalf(const float4* __restrict__ in,
                                                uint2* __restrict__ outh, int n4) {
    for (int i = blockIdx.x * blockDim.x + threadIdx.x; i < n4; i += gridDim.x * blockDim.x) {
        float4 v = in[i];
        uint2 o;
        o.x = h2u(__halves2half2(__float2half_rn(v.x), __float2half_rn(v.y)));
        o.y = h2u(__halves2half2(__float2half_rn(v.z), __float2half_rn(v.w)));
        outh[i] = o;
    }
}

// ---------------------------------------------------------------------------
// Exclusive scan of in-degree (deg-1) -> rowstart  (1024 elems/block)
// ---------------------------------------------------------------------------
__global__ void k_scan_partial(const int* __restrict__ deg, int* __restrict__ part, int N) {
    __shared__ int sh[256];
    int base = blockIdx.x * 1024 + threadIdx.x * 4;
    int s = 0;
#pragma unroll
    for (int q = 0; q < 4; ++q) {
        int i = base + q;
        if (i < N) s += deg[i] - 1;
    }
    sh[threadIdx.x] = s;
    __syncthreads();
    for (int off = 128; off > 0; off >>= 1) {
        if (threadIdx.x < off) sh[threadIdx.x] += sh[threadIdx.x + off];
        __syncthreads();
    }
    if (threadIdx.x == 0) part[blockIdx.x] = sh[0];
}

__global__ void k_scan_offsets(int* __restrict__ part, int* __restrict__ rowstart, int nb, int N) {
    int run = 0;
    for (int i = 0; i < nb; ++i) { int v = part[i]; part[i] = run; run += v; }
    rowstart[N] = run;   // == E
}

__global__ void k_scan_write(const int* __restrict__ deg, const int* __restrict__ part,
                             int* __restrict__ rowstart, int N) {
    __shared__ int sh[256];
    int base = blockIdx.x * 1024 + threadIdx.x * 4;
    int v[4]; int s = 0;
#pragma unroll
    for (int q = 0; q < 4; ++q) {
        int i = base + q;
        v[q] = (i < N) ? deg[i] - 1 : 0;
        s += v[q];
    }
    sh[threadIdx.x] = s;
    __syncthreads();
    if (threadIdx.x == 0) {
        int run = part[blockIdx.x];
        for (int t = 0; t < 256; ++t) { int x = sh[t]; sh[t] = run; run += x; }
    }
    __syncthreads();
    int run = sh[threadIdx.x];
#pragma unroll
    for (int q = 0; q < 4; ++q) {
        int i = base + q;
        if (i < N) { rowstart[i] = run; run += v[q]; }
    }
}

// ---------------------------------------------------------------------------
// Bucketed CSR fill.
// gcur[b] pre-init to rowstart[b*NPB] -> bucket regions tile col exactly.
// Pass 1: per-block histogram + space reservation + (src,dst) scatter to stage.
// Pass 2: one block per bucket; scatter src in LDS, stream out coalesced.
// ---------------------------------------------------------------------------
__global__ void k_bucket_init(const int* __restrict__ rowstart, int* __restrict__ gcur,
                              int N, int nbuck) {
    int b = blockIdx.x * blockDim.x + threadIdx.x;
    if (b < nbuck) {
        int n = b * NPB;
        gcur[b] = rowstart[n < N ? n : N];
    }
}

__global__ __launch_bounds__(256) void k_binfill(const int* __restrict__ src,
                                                 const int* __restrict__ dst,
                                                 int* __restrict__ gcur,
                                                 uint2* __restrict__ stage,
                                                 int E, int nbuck) {
    __shared__ int hist[MAXBUCK];
    __shared__ int base[MAXBUCK];
    int tid = threadIdx.x;
    int chunk = (E + gridDim.x - 1) / gridDim.x;
    int e0 = blockIdx.x * chunk;
    int e1 = min(E, e0 + chunk);
    for (int b = tid; b < nbuck; b += 256) hist[b] = 0;
    __syncthreads();
    for (int e = e0 + tid; e < e1; e += 256)
        atomicAdd(&hist[dst[e] >> 8], 1);
    __syncthreads();
    for (int b = tid; b < nbuck; b += 256)
        base[b] = atomicAdd(&gcur[b], hist[b]);
    __syncthreads();
    for (int b = tid; b < nbuck; b += 256) hist[b] = 0;   // reuse as cursor
    __syncthreads();
    for (int e = e0 + tid; e < e1; e += 256) {
        int d = dst[e];
        int bk = d >> 8;
        int p = base[bk] + atomicAdd(&hist[bk], 1);
        stage[p] = make_uint2((unsigned)src[e], (unsigned)d);
    }
}

__global__ __launch_bounds__(256) void k_csrbuild(const uint2* __restrict__ stage,
                                                  const int* __restrict__ rowstart,
                                                  int* __restrict__ col, int N) {
    __shared__ int cur[NPB];
    __shared__ int lcol[CAP];
    int b   = blockIdx.x;
    int tid = threadIdx.x;
    int n0  = b << 8;
    int n1  = min(N, n0 + NPB);
    int r0  = rowstart[n0];
    int r1  = rowstart[n1];
    int cnt = r1 - r0;
    if (n0 + tid < n1) cur[tid] = rowstart[n0 + tid] - r0;
    __syncthreads();
    if (cnt <= CAP) {
        for (int i = tid; i < cnt; i += 256) {
            uint2 rec = stage[r0 + i];
            int p = atomicAdd(&cur[(int)rec.y - n0], 1);
            lcol[p] = (int)rec.x;
        }
        __syncthreads();
        for (int i = tid; i < cnt; i += 256)
            col[r0 + i] = lcol[i];
    } else {
        // overflow fallback (not expected for uniform-random dst)
        for (int i = tid; i < cnt; i += 256) {
            uint2 rec = stage[r0 + i];
            int p = atomicAdd(&cur[(int)rec.y - n0], 1);
            col[r0 + p] = (int)rec.x;
        }
    }
}

// ---------------------------------------------------------------------------
// Aggregation over fp16 table, fp32 accumulate.
// out[i] = dinv[i] * ( sum_j dinv[j]*x[j] + dinv[i]*x[i] )
// one wave per node; lane = 4-half (8B) column slice. fp16 output.
// ---------------------------------------------------------------------------
__global__ __launch_bounds__(256) void k_agg_h2h(const uint2* __restrict__ xh,
                                                 const float* __restrict__ dinv,
                                                 const int* __restrict__ rowstart,
                                                 const int* __restrict__ col,
                                                 uint2* __restrict__ outh,
                                                 float* __restrict__ rs, int N, int writeRs) {
    int wave = (blockIdx.x * blockDim.x + threadIdx.x) >> 6;
    int lane = threadIdx.x & 63;
    if (wave >= N) return;
    float di = dinv[wave];
    uint2 xraw = xh[(size_t)wave * DIMH2 + lane];
    float2 f0 = __half22float2(u2h(xraw.x));
    float2 f1 = __half22float2(u2h(xraw.y));
    float ax = di * f0.x, ay = di * f0.y, az = di * f1.x, aw = di * f1.y;
    float sd = 0.f;
    int p = rowstart[wave], e = rowstart[wave + 1];
    if (p < e) {
        int j = col[p]; float dj = dinv[j];
        for (++p; p < e; ++p) {
            int jn = col[p]; float djn = dinv[jn];      // prefetch next
            uint2 raw = xh[(size_t)j * DIMH2 + lane];
            float2 v0 = __half22float2(u2h(raw.x));
            float2 v1 = __half22float2(u2h(raw.y));
            ax += dj * v0.x; ay += dj * v0.y; az += dj * v1.x; aw += dj * v1.y;
            sd += dj;
            j = jn; dj = djn;
        }
        uint2 raw = xh[(size_t)j * DIMH2 + lane];
        float2 v0 = __half22float2(u2h(raw.x));
        float2 v1 = __half22float2(u2h(raw.y));
        ax += dj * v0.x; ay += dj * v0.y; az += dj * v1.x; aw += dj * v1.y;
        sd += dj;
    }
    uint2 o;
    o.x = h2u(__halves2half2(__float2half_rn(di * ax), __float2half_rn(di * ay)));
    o.y = h2u(__halves2half2(__float2half_rn(di * az), __float2half_rn(di * aw)));
    outh[(size_t)wave * DIMH2 + lane] = o;
    if (writeRs && lane == 0) rs[wave] = di * (sd + di);
}

// ---------------------------------------------------------------------------
// Weight collapse: WcT[j][i] = fp16( (W1 @ W2)[i][j] ); cvec = b1 @ W2 (fp32)
// ---------------------------------------------------------------------------
__global__ void k_wct(const float* __restrict__ W1, const float* __restrict__ W2,
                      _Float16* __restrict__ WcT) {
    int i = blockIdx.x, j = threadIdx.x;
    float acc = 0.f;
    for (int k = 0; k < 2 * DIM; ++k) acc += W1[i * 2 * DIM + k] * W2[k * DIM + j];
    WcT[(size_t)j * DIM + i] = (_Float16)acc;
}

__global__ void k_cvec(const float* __restrict__ b1, const float* __restrict__ W2,
                       float* __restrict__ cvec) {
    int j = threadIdx.x;
    float acc = 0.f;
    for (int k = 0; k < 2 * DIM; ++k) acc += b1[k] * W2[k * DIM + j];
    cvec[j] = acc;
}

// ---------------------------------------------------------------------------
// MFMA GEMM: C[N,256] = Ah[N,256] @ Wc + rs⊗cvec + b2   (fp16 in, fp32 out)
// B supplied transposed (WcT[col][k]) so both operands stage as [row][k].
// Block 256 thr = 4 waves (2x2), tile 128x128, wave tile 64x64 = 4x4 frags
// of v_mfma_f32_16x16x32_f16. K loop: 8 steps of 32.
// Fragment maps (gfx950 16x16x32): A/B lane l: row|col = l%16, k=(l/16)*8+j.
// C/D lane l reg r: col = l&15, row = (l>>4)*4 + r   [learn_hip m89].
// ---------------------------------------------------------------------------
#define GBM 128
#define GBN 128
#define ASTR 40   // halves; 32 + 8 pad → 80B row stride, 16B aligned, 2-way banks

__global__ __launch_bounds__(256) void k_gemm_mfma(const _Float16* __restrict__ Ah,
                                                   const _Float16* __restrict__ BTh,
                                                   const float* __restrict__ rs,
                                                   const float* __restrict__ cvec,
                                                   const float* __restrict__ b2,
                                                   float* __restrict__ C, int N) {
    __shared__ _Float16 As[GBM][ASTR];
    __shared__ _Float16 Bs[GBN][ASTR];
    int tid  = threadIdx.x;
    int row0 = blockIdx.x * GBM;
    int col0 = blockIdx.y * GBN;
    int w    = tid >> 6;
    int lane = tid & 63;
    int wr   = (w >> 1) * 64;    // wave row offset in tile
    int wc   = (w & 1) * 64;     // wave col offset in tile
    int lr   = lane & 15;
    int kg   = lane >> 4;        // 0..3

    f32x4 acc[4][4];
#pragma unroll
    for (int i = 0; i < 4; ++i)
#pragma unroll
        for (int j = 0; j < 4; ++j) acc[i][j] = (f32x4)0.f;

    int sr = tid >> 2;           // 0..63 (two rows per thread: sr, sr+64)
    int sc = (tid & 3) * 8;      // half offset within 32-k row

    for (int k0 = 0; k0 < DIM; k0 += 32) {
        __syncthreads();
#pragma unroll
        for (int q = 0; q < 2; ++q) {
            int r  = sr + q * 64;
            int gr = row0 + r;
            half8 av = (half8)(_Float16)0.f;
            if (gr < N)
                av = *reinterpret_cast<const half8*>(&Ah[(size_t)gr * DIM + k0 + sc]);
            *reinterpret_cast<half8*>(&As[r][sc]) = av;
            half8 bv = *reinterpret_cast<const half8*>(&BTh[(size_t)(col0 + r) * DIM + k0 + sc]);
            *reinterpret_cast<half8*>(&Bs[r][sc]) = bv;
        }
        __syncthreads();

        half8 af[4], bf[4];
#pragma unroll
        for (int mm = 0; mm < 4; ++mm)
            af[mm] = *reinterpret_cast<const half8*>(&As[wr + mm * 16 + lr][kg * 8]);
#pragma unroll
        for (int nn = 0; nn < 4; ++nn)
            bf[nn] = *reinterpret_cast<const half8*>(&Bs[wc + nn * 16 + lr][kg * 8]);
#pragma unroll
        for (int mm = 0; mm < 4; ++mm)
#pragma unroll
            for (int nn = 0; nn < 4; ++nn)
                acc[mm][nn] = __builtin_amdgcn_mfma_f32_16x16x32_f16(af[mm], bf[nn],
                                                                     acc[mm][nn], 0, 0, 0);
    }

#pragma unroll
    for (int mm = 0; mm < 4; ++mm) {
        int rbase = row0 + wr + mm * 16 + kg * 4;
#pragma unroll
        for (int reg = 0; reg < 4; ++reg) {
            int r = rbase + reg;
            if (r < N) {
                float rv = rs[r];
#pragma unroll
                for (int nn = 0; nn < 4; ++nn) {
                    int c = col0 + wc + nn * 16 + lr;
                    C[(size_t)r * DIM + c] = acc[mm][nn][reg] + rv * cvec[c] + b2[c];
                }
            }
        }
    }
}

// ---------------------------------------------------------------------------
// BatchNorm (training-mode, biased var) over axis 0
// ---------------------------------------------------------------------------
__global__ void k_bnzero(float* __restrict__ p) {
    p[threadIdx.x] = 0.f;   // 512 threads: sum[256] + sumsq[256]
}

__global__ __launch_bounds__(256) void k_bnstats(const float* __restrict__ h,
                                                 float* __restrict__ sum,
                                                 float* __restrict__ sq, int N) {
    int ch = threadIdx.x;
    float s = 0.f, ss = 0.f;
    for (int r = blockIdx.x; r < N; r += gridDim.x) {
        float v = h[r * DIM + ch];
        s += v; ss += v * v;
    }
    atomicAdd(&sum[ch], s);
    atomicAdd(&sq[ch], ss);
}

__global__ void k_bnfinal(const float* __restrict__ sum, const float* __restrict__ sq,
                          const float* __restrict__ gamma, const float* __restrict__ beta,
                          float* __restrict__ scale, float* __restrict__ shift, int N) {
    int ch = threadIdx.x;
    float invN = 1.0f / (float)N;
    float mean = sum[ch] * invN;
    float var = sq[ch] * invN - mean * mean;
    float inv = rsqrtf(var + BN_EPS);
    float sc = gamma[ch] * inv;
    scale[ch] = sc;
    shift[ch] = beta[ch] - mean * sc;
}

__global__ __launch_bounds__(256) void k_bnnorm(float4* __restrict__ out,
                                                const float4* __restrict__ scale,
                                                const float4* __restrict__ shift, int n4) {
    for (int i = blockIdx.x * blockDim.x + threadIdx.x; i < n4; i += gridDim.x * blockDim.x) {
        int j = i & (DIM4 - 1);
        float4 v = out[i];
        float4 sc = scale[j];
        float4 sh = shift[j];
        v.x = v.x * sc.x + sh.x;
        v.y = v.y * sc.y + sh.y;
        v.z = v.z * sc.z + sh.z;
        v.w = v.w * sc.w + sh.w;
        out[i] = v;
    }
}

// ---------------------------------------------------------------------------
extern "C" void kernel_launch(void* const* d_in, const int* in_sizes, int n_in,
                              void* d_out, int out_size, void* d_ws, size_t ws_size,
                              hipStream_t stream) {
    const int* ei        = (const int*)d_in[0];     // int32 per harness convention
    const float* emb     = (const float*)d_in[1];
    const float* W1      = (const float*)d_in[2];
    const float* b1      = (const float*)d_in[3];
    const float* W2      = (const float*)d_in[4];
    const float* b2      = (const float*)d_in[5];
    const float* gamma   = (const float*)d_in[6];
    const float* beta    = (const float*)d_in[7];

    const int E = in_sizes[0] / 2;
    const int N = in_sizes[1] / DIM;
    const int* src = ei;
    const int* dst = ei + E;
    const int nbuck = (N + NPB - 1) / NPB;          // 391 for N=100000

    // workspace carve-up (256B aligned) — ~93MB, below proven ~118MB budget
    char* w = (char*)d_ws;
    size_t off = 0;
    auto alloc = [&](size_t bytes) -> void* {
        off = (off + 255) & ~(size_t)255;
        void* p = w + off;
        off += bytes;
        return p;
    };
    int*      deg      = (int*)     alloc((size_t)N * 4);
    float*    dinv     = (float*)   alloc((size_t)N * 4);
    int*      rowstart = (int*)     alloc((size_t)(N + 1) * 4);
    int*      gcur     = (int*)     alloc((size_t)(nbuck + 1) * 4);
    int*      part     = (int*)     alloc(1024);
    int*      csr_col  = (int*)     alloc((size_t)E * 4);
    uint2*    stage    = (uint2*)   alloc((size_t)E * 8);
    float*    rs       = (float*)   alloc((size_t)N * 4);
    uint2*    agg2h    = (uint2*)   alloc((size_t)N * DIM * 2);   // fp16 [N,256]
    _Float16* WcTh     = (_Float16*)alloc((size_t)DIM * DIM * 2); // fp16 Wc^T
    float*    cvec     = (float*)   alloc(DIM * 4);
    float*    bnsum    = (float*)   alloc(2 * DIM * 4);   // sum | sumsq
    float*    bnscale  = (float*)   alloc(2 * DIM * 4);   // scale | shift

    // fp16 tables alias d_out (dead until the GEMM writes it):
    //   [0, N*DIM*2)        xh    = fp16(emb)
    //   [N*DIM*2, N*DIM*4)  agg1h = fp16(A @ emb)
    uint2* xh    = (uint2*)d_out;
    uint2* agg1h = (uint2*)((char*)d_out + (size_t)N * DIM * 2);
    float* out   = (float*)d_out;

    const int nb1024 = (N + 1023) / 1024;

    // 1. degree + dinv
    k_deg_init<<<(N + 255) / 256, 256, 0, stream>>>(deg, N);
    k_deg_count<<<2048, 256, 0, stream>>>(dst, deg, E);
    k_dinv<<<(N + 255) / 256, 256, 0, stream>>>(deg, dinv, N);

    // 2. fp16 gather table of emb
    k_tohalf<<<2048, 256, 0, stream>>>((const float4*)emb, xh, N * DIM4);

    // 3. CSR build (bucketed two-pass fill)
    k_scan_partial<<<nb1024, 256, 0, stream>>>(deg, part, N);
    k_scan_offsets<<<1, 1, 0, stream>>>(part, rowstart, nb1024, N);
    k_scan_write<<<nb1024, 256, 0, stream>>>(deg, part, rowstart, N);
    k_bucket_init<<<(nbuck + 255) / 256, 256, 0, stream>>>(rowstart, gcur, N, nbuck);
    k_binfill<<<256, 256, 0, stream>>>(src, dst, gcur, stage, E, nbuck);
    k_csrbuild<<<nbuck, 256, 0, stream>>>(stage, rowstart, csr_col, N);

    // 4. agg1h = fp16(A @ x); rs = A @ 1
    k_agg_h2h<<<(N + 3) / 4, 256, 0, stream>>>(xh, dinv, rowstart, csr_col, agg1h, rs, N, 1);
    // 5. agg2h = fp16(A @ agg1)
    k_agg_h2h<<<(N + 3) / 4, 256, 0, stream>>>(agg1h, dinv, rowstart, csr_col, agg2h, rs, N, 0);

    // 6. weight collapse (fp16 transposed for MFMA B-operand)
    k_wct<<<DIM, DIM, 0, stream>>>(W1, W2, WcTh);
    k_cvec<<<1, DIM, 0, stream>>>(b1, W2, cvec);

    // 7. h2 = agg2 @ Wc + rs⊗cvec + b2  -> d_out (overwrites dead fp16 tables)
    dim3 ggrid((N + GBM - 1) / GBM, DIM / GBN);
    k_gemm_mfma<<<ggrid, 256, 0, stream>>>((const _Float16*)agg2h, WcTh, rs, cvec, b2, out, N);

    // 8. BatchNorm
    k_bnzero<<<1, 512, 0, stream>>>(bnsum);
    k_bnstats<<<512, 256, 0, stream>>>(out, bnsum, bnsum + DIM, N);
    k_bnfinal<<<1, DIM, 0, stream>>>(bnsum, bnsum + DIM, gamma, beta,
                                     bnscale, bnscale + DIM, N);
    k_bnnorm<<<2048, 256, 0, stream>>>((float4*)out, (const float4*)bnscale,
                                       (const float4*)(bnscale + DIM), N * DIM4);
}

// Round 11
// 1076.493 us; speedup vs baseline: 1.7239x; 1.0130x over previous
//
#include <hip/hip_runtime.h>
#include <hip/hip_fp16.h>
#include <math.h>

// Problem constants
#define DIM   256
#define DIM4  64          // DIM/4 float4 per row
#define DIMH2 64          // DIM/4 halves-packed-as-uint2 per row (4 halves each)
#define BN_EPS 1e-5f

// Bucketed CSR-fill parameters
#define NPB      256      // nodes per bucket (pow2: bucket = dst >> 8)
#define MAXBUCK  512      // static LDS bound on bucket count (need 391)
#define CAP      13312    // per-bucket LDS edge capacity (avg 8192, +6 sigma ~8.7K)

typedef __attribute__((ext_vector_type(8))) _Float16 half8;
typedef __attribute__((ext_vector_type(4))) float f32x4;

__device__ __forceinline__ unsigned h2u(__half2 h) { return __builtin_bit_cast(unsigned, h); }
__device__ __forceinline__ __half2 u2h(unsigned u) { return __builtin_bit_cast(__half2, u); }

// ---------------------------------------------------------------------------
// Degree / dinv
// ---------------------------------------------------------------------------
__global__ void k_deg_init(int* __restrict__ deg, int N) {
    int i = blockIdx.x * blockDim.x + threadIdx.x;
    if (i < N) deg[i] = 1;   // self-loop
}

__global__ void k_deg_count(const int* __restrict__ dst, int* __restrict__ deg, int E) {
    for (int e = blockIdx.x * blockDim.x + threadIdx.x; e < E; e += gridDim.x * blockDim.x) {
        atomicAdd(&deg[dst[e]], 1);
    }
}

__global__ void k_dinv(const int* __restrict__ deg, float* __restrict__ dinv, int N) {
    int i = blockIdx.x * blockDim.x + threadIdx.x;
    if (i < N) dinv[i] = rsqrtf((float)deg[i]);
}

// ---------------------------------------------------------------------------
// u-table build: uh[i] = fp16( dinv[row] * emb[i] )   (4 floats/thread-iter)
// ---------------------------------------------------------------------------
__global__ __launch_bounds__(256) void k_tohalf_u(const float4* __restrict__ in,
                                                  const float* __restrict__ dinv,
                                                  uint2* __restrict__ outh, int n4) {
    for (int i = blockIdx.x * blockDim.x + threadIdx.x; i < n4; i += gridDim.x * blockDim.x) {
        float d = dinv[i >> 6];           // row = i / DIM4
        float4 v = in[i];
        uint2 o;
        o.x = h2u(__halves2half2(__float2half_rn(d * v.x), __float2half_rn(d * v.y)));
        o.y = h2u(__halves2half2(__float2half_rn(d * v.z), __float2half_rn(d * v.w)));
        outh[i] = o;
    }
}

// ---------------------------------------------------------------------------
// Exclusive scan of in-degree (deg-1) -> rowstart  (1024 elems/block)
// ---------------------------------------------------------------------------
__global__ void k_scan_partial(const int* __restrict__ deg, int* __restrict__ part, int N) {
    __shared__ int sh[256];
    int base = blockIdx.x * 1024 + threadIdx.x * 4;
    int s = 0;
#pragma unroll
    for (int q = 0; q < 4; ++q) {
        int i = base + q;
        if (i < N) s += deg[i] - 1;
    }
    sh[threadIdx.x] = s;
    __syncthreads();
    for (int off = 128; off > 0; off >>= 1) {
        if (threadIdx.x < off) sh[threadIdx.x] += sh[threadIdx.x + off];
        __syncthreads();
    }
    if (threadIdx.x == 0) part[blockIdx.x] = sh[0];
}

__global__ void k_scan_offsets(int* __restrict__ part, int* __restrict__ rowstart, int nb, int N) {
    int run = 0;
    for (int i = 0; i < nb; ++i) { int v = part[i]; part[i] = run; run += v; }
    rowstart[N] = run;   // == E
}

__global__ void k_scan_write(const int* __restrict__ deg, const int* __restrict__ part,
                             int* __restrict__ rowstart, int N) {
    __shared__ int sh[256];
    int base = blockIdx.x * 1024 + threadIdx.x * 4;
    int v[4]; int s = 0;
#pragma unroll
    for (int q = 0; q < 4; ++q) {
        int i = base + q;
        v[q] = (i < N) ? deg[i] - 1 : 0;
        s += v[q];
    }
    sh[threadIdx.x] = s;
    __syncthreads();
    if (threadIdx.x == 0) {
        int run = part[blockIdx.x];
        for (int t = 0; t < 256; ++t) { int x = sh[t]; sh[t] = run; run += x; }
    }
    __syncthreads();
    int run = sh[threadIdx.x];
#pragma unroll
    for (int q = 0; q < 4; ++q) {
        int i = base + q;
        if (i < N) { rowstart[i] = run; run += v[q]; }
    }
}

// ---------------------------------------------------------------------------
// Bucketed CSR fill (two-pass; see R9 notes — avoids 16x write amplification)
// ---------------------------------------------------------------------------
__global__ void k_bucket_init(const int* __restrict__ rowstart, int* __restrict__ gcur,
                              int N, int nbuck) {
    int b = blockIdx.x * blockDim.x + threadIdx.x;
    if (b < nbuck) {
        int n = b * NPB;
        gcur[b] = rowstart[n < N ? n : N];
    }
}

__global__ __launch_bounds__(256) void k_binfill(const int* __restrict__ src,
                                                 const int* __restrict__ dst,
                                                 int* __restrict__ gcur,
                                                 uint2* __restrict__ stage,
                                                 int E, int nbuck) {
    __shared__ int hist[MAXBUCK];
    __shared__ int base[MAXBUCK];
    int tid = threadIdx.x;
    int chunk = (E + gridDim.x - 1) / gridDim.x;
    int e0 = blockIdx.x * chunk;
    int e1 = min(E, e0 + chunk);
    for (int b = tid; b < nbuck; b += 256) hist[b] = 0;
    __syncthreads();
    for (int e = e0 + tid; e < e1; e += 256)
        atomicAdd(&hist[dst[e] >> 8], 1);
    __syncthreads();
    for (int b = tid; b < nbuck; b += 256)
        base[b] = atomicAdd(&gcur[b], hist[b]);
    __syncthreads();
    for (int b = tid; b < nbuck; b += 256) hist[b] = 0;   // reuse as cursor
    __syncthreads();
    for (int e = e0 + tid; e < e1; e += 256) {
        int d = dst[e];
        int bk = d >> 8;
        int p = base[bk] + atomicAdd(&hist[bk], 1);
        stage[p] = make_uint2((unsigned)src[e], (unsigned)d);
    }
}

__global__ __launch_bounds__(256) void k_csrbuild(const uint2* __restrict__ stage,
                                                  const int* __restrict__ rowstart,
                                                  int* __restrict__ col, int N) {
    __shared__ int cur[NPB];
    __shared__ int lcol[CAP];
    int b   = blockIdx.x;
    int tid = threadIdx.x;
    int n0  = b << 8;
    int n1  = min(N, n0 + NPB);
    int r0  = rowstart[n0];
    int r1  = rowstart[n1];
    int cnt = r1 - r0;
    if (n0 + tid < n1) cur[tid] = rowstart[n0 + tid] - r0;
    __syncthreads();
    if (cnt <= CAP) {
        for (int i = tid; i < cnt; i += 256) {
            uint2 rec = stage[r0 + i];
            int p = atomicAdd(&cur[(int)rec.y - n0], 1);
            lcol[p] = (int)rec.x;
        }
        __syncthreads();
        for (int i = tid; i < cnt; i += 256)
            col[r0 + i] = lcol[i];
    } else {
        // overflow fallback (not expected for uniform-random dst)
        for (int i = tid; i < cnt; i += 256) {
            uint2 rec = stage[r0 + i];
            int p = atomicAdd(&cur[(int)rec.y - n0], 1);
            col[r0 + p] = (int)rec.x;
        }
    }
}

// ---------------------------------------------------------------------------
// rs = A @ 1 : rs[i] = dinv[i] * ( sum_j dinv[col[j]] + dinv[i] )
// one wave per node, lanes parallel over neighbors, butterfly reduce.
// ---------------------------------------------------------------------------
__global__ __launch_bounds__(256) void k_rs(const float* __restrict__ dinv,
                                            const int* __restrict__ rowstart,
                                            const int* __restrict__ col,
                                            float* __restrict__ rs, int N) {
    int wave = (blockIdx.x * blockDim.x + threadIdx.x) >> 6;
    int lane = threadIdx.x & 63;
    if (wave >= N) return;
    int s = rowstart[wave], e = rowstart[wave + 1];
    float sd = 0.f;
    for (int p = s + lane; p < e; p += 64) sd += dinv[col[p]];
#pragma unroll
    for (int off = 32; off > 0; off >>= 1) sd += __shfl_xor(sd, off);
    if (lane == 0) {
        float di = dinv[wave];
        rs[wave] = di * (sd + di);
    }
}

// ---------------------------------------------------------------------------
// Aggregation over pre-scaled fp16 u-table, fp32 accumulate.
//   u[j] = dinv[j]*x[j];  out[i] = fp16( s_i * ( sum_{j in N(i)} u[j] + u[i] ) )
//   pass 1: s_i = dinv^2 (emits next pass's u-table);  pass 2: s_i = dinv (y2).
// One wave per node; lane = 4-half (8B) slice. Neighbor loop unrolled x4 so
// 4 independent 512B row-gathers are in flight per wave (MLP).
// ---------------------------------------------------------------------------
__global__ __launch_bounds__(256) void k_agg_u(const uint2* __restrict__ uh,
                                               const float* __restrict__ dinv,
                                               const int* __restrict__ rowstart,
                                               const int* __restrict__ col,
                                               uint2* __restrict__ outh,
                                               int N, int squareDi) {
    int wave = (blockIdx.x * blockDim.x + threadIdx.x) >> 6;
    int lane = threadIdx.x & 63;
    if (wave >= N) return;
    uint2 uself = uh[(size_t)wave * DIMH2 + lane];
    float2 f0 = __half22float2(u2h(uself.x));
    float2 f1 = __half22float2(u2h(uself.y));
    float ax = f0.x, ay = f0.y, az = f1.x, aw = f1.y;
    int p = rowstart[wave], e = rowstart[wave + 1];
    for (; p + 3 < e; p += 4) {
        int j0 = col[p], j1 = col[p + 1], j2 = col[p + 2], j3 = col[p + 3];
        uint2 r0 = uh[(size_t)j0 * DIMH2 + lane];
        uint2 r1 = uh[(size_t)j1 * DIMH2 + lane];
        uint2 r2 = uh[(size_t)j2 * DIMH2 + lane];
        uint2 r3 = uh[(size_t)j3 * DIMH2 + lane];
        float2 a0 = __half22float2(u2h(r0.x)), b0 = __half22float2(u2h(r0.y));
        float2 a1 = __half22float2(u2h(r1.x)), b1 = __half22float2(u2h(r1.y));
        float2 a2 = __half22float2(u2h(r2.x)), b2 = __half22float2(u2h(r2.y));
        float2 a3 = __half22float2(u2h(r3.x)), b3 = __half22float2(u2h(r3.y));
        ax += (a0.x + a1.x) + (a2.x + a3.x);
        ay += (a0.y + a1.y) + (a2.y + a3.y);
        az += (b0.x + b1.x) + (b2.x + b3.x);
        aw += (b0.y + b1.y) + (b2.y + b3.y);
    }
    for (; p < e; ++p) {
        int j = col[p];
        uint2 r = uh[(size_t)j * DIMH2 + lane];
        float2 a = __half22float2(u2h(r.x)), b = __half22float2(u2h(r.y));
        ax += a.x; ay += a.y; az += b.x; aw += b.y;
    }
    float di = dinv[wave];
    float s = squareDi ? di * di : di;
    uint2 o;
    o.x = h2u(__halves2half2(__float2half_rn(s * ax), __float2half_rn(s * ay)));
    o.y = h2u(__halves2half2(__float2half_rn(s * az), __float2half_rn(s * aw)));
    outh[(size_t)wave * DIMH2 + lane] = o;
}

// ---------------------------------------------------------------------------
// Weight collapse: WcT[j][i] = fp16( (W1 @ W2)[i][j] ); cvec = b1 @ W2 (fp32)
// ---------------------------------------------------------------------------
__global__ void k_wct(const float* __restrict__ W1, const float* __restrict__ W2,
                      _Float16* __restrict__ WcT) {
    int i = blockIdx.x, j = threadIdx.x;
    float acc = 0.f;
    for (int k = 0; k < 2 * DIM; ++k) acc += W1[i * 2 * DIM + k] * W2[k * DIM + j];
    WcT[(size_t)j * DIM + i] = (_Float16)acc;
}

__global__ void k_cvec(const float* __restrict__ b1, const float* __restrict__ W2,
                       float* __restrict__ cvec) {
    int j = threadIdx.x;
    float acc = 0.f;
    for (int k = 0; k < 2 * DIM; ++k) acc += b1[k] * W2[k * DIM + j];
    cvec[j] = acc;
}

// ---------------------------------------------------------------------------
// MFMA GEMM: C[N,256] = Ah[N,256] @ Wc + rs⊗cvec + b2   (fp16 in, fp32 out)
// (validated R9; fragment maps per learn_hip m89)
// ---------------------------------------------------------------------------
#define GBM 128
#define GBN 128
#define ASTR 40   // halves; 32 + 8 pad → 80B row stride, 16B aligned, 2-way banks

__global__ __launch_bounds__(256) void k_gemm_mfma(const _Float16* __restrict__ Ah,
                                                   const _Float16* __restrict__ BTh,
                                                   const float* __restrict__ rs,
                                                   const float* __restrict__ cvec,
                                                   const float* __restrict__ b2,
                                                   float* __restrict__ C, int N) {
    __shared__ _Float16 As[GBM][ASTR];
    __shared__ _Float16 Bs[GBN][ASTR];
    int tid  = threadIdx.x;
    int row0 = blockIdx.x * GBM;
    int col0 = blockIdx.y * GBN;
    int w    = tid >> 6;
    int lane = tid & 63;
    int wr   = (w >> 1) * 64;    // wave row offset in tile
    int wc   = (w & 1) * 64;     // wave col offset in tile
    int lr   = lane & 15;
    int kg   = lane >> 4;        // 0..3

    f32x4 acc[4][4];
#pragma unroll
    for (int i = 0; i < 4; ++i)
#pragma unroll
        for (int j = 0; j < 4; ++j) acc[i][j] = (f32x4)0.f;

    int sr = tid >> 2;           // 0..63 (two rows per thread: sr, sr+64)
    int sc = (tid & 3) * 8;      // half offset within 32-k row

    for (int k0 = 0; k0 < DIM; k0 += 32) {
        __syncthreads();
#pragma unroll
        for (int q = 0; q < 2; ++q) {
            int r  = sr + q * 64;
            int gr = row0 + r;
            half8 av = (half8)(_Float16)0.f;
            if (gr < N)
                av = *reinterpret_cast<const half8*>(&Ah[(size_t)gr * DIM + k0 + sc]);
            *reinterpret_cast<half8*>(&As[r][sc]) = av;
            half8 bv = *reinterpret_cast<const half8*>(&BTh[(size_t)(col0 + r) * DIM + k0 + sc]);
            *reinterpret_cast<half8*>(&Bs[r][sc]) = bv;
        }
        __syncthreads();

        half8 af[4], bf[4];
#pragma unroll
        for (int mm = 0; mm < 4; ++mm)
            af[mm] = *reinterpret_cast<const half8*>(&As[wr + mm * 16 + lr][kg * 8]);
#pragma unroll
        for (int nn = 0; nn < 4; ++nn)
            bf[nn] = *reinterpret_cast<const half8*>(&Bs[wc + nn * 16 + lr][kg * 8]);
#pragma unroll
        for (int mm = 0; mm < 4; ++mm)
#pragma unroll
            for (int nn = 0; nn < 4; ++nn)
                acc[mm][nn] = __builtin_amdgcn_mfma_f32_16x16x32_f16(af[mm], bf[nn],
                                                                     acc[mm][nn], 0, 0, 0);
    }

#pragma unroll
    for (int mm = 0; mm < 4; ++mm) {
        int rbase = row0 + wr + mm * 16 + kg * 4;
#pragma unroll
        for (int reg = 0; reg < 4; ++reg) {
            int r = rbase + reg;
            if (r < N) {
                float rv = rs[r];
#pragma unroll
                for (int nn = 0; nn < 4; ++nn) {
                    int c = col0 + wc + nn * 16 + lr;
                    C[(size_t)r * DIM + c] = acc[mm][nn][reg] + rv * cvec[c] + b2[c];
                }
            }
        }
    }
}

// ---------------------------------------------------------------------------
// BatchNorm (training-mode, biased var) over axis 0
// ---------------------------------------------------------------------------
__global__ void k_bnzero(float* __restrict__ p) {
    p[threadIdx.x] = 0.f;   // 512 threads: sum[256] + sumsq[256]
}

__global__ __launch_bounds__(256) void k_bnstats(const float* __restrict__ h,
                                                 float* __restrict__ sum,
                                                 float* __restrict__ sq, int N) {
    int ch = threadIdx.x;
    float s = 0.f, ss = 0.f;
    for (int r = blockIdx.x; r < N; r += gridDim.x) {
        float v = h[r * DIM + ch];
        s += v; ss += v * v;
    }
    atomicAdd(&sum[ch], s);
    atomicAdd(&sq[ch], ss);
}

__global__ void k_bnfinal(const float* __restrict__ sum, const float* __restrict__ sq,
                          const float* __restrict__ gamma, const float* __restrict__ beta,
                          float* __restrict__ scale, float* __restrict__ shift, int N) {
    int ch = threadIdx.x;
    float invN = 1.0f / (float)N;
    float mean = sum[ch] * invN;
    float var = sq[ch] * invN - mean * mean;
    float inv = rsqrtf(var + BN_EPS);
    float sc = gamma[ch] * inv;
    scale[ch] = sc;
    shift[ch] = beta[ch] - mean * sc;
}

__global__ __launch_bounds__(256) void k_bnnorm(float4* __restrict__ out,
                                                const float4* __restrict__ scale,
                                                const float4* __restrict__ shift, int n4) {
    for (int i = blockIdx.x * blockDim.x + threadIdx.x; i < n4; i += gridDim.x * blockDim.x) {
        int j = i & (DIM4 - 1);
        float4 v = out[i];
        float4 sc = scale[j];
        float4 sh = shift[j];
        v.x = v.x * sc.x + sh.x;
        v.y = v.y * sc.y + sh.y;
        v.z = v.z * sc.z + sh.z;
        v.w = v.w * sc.w + sh.w;
        out[i] = v;
    }
}

// ---------------------------------------------------------------------------
extern "C" void kernel_launch(void* const* d_in, const int* in_sizes, int n_in,
                              void* d_out, int out_size, void* d_ws, size_t ws_size,
                              hipStream_t stream) {
    const int* ei        = (const int*)d_in[0];     // int32 per harness convention
    const float* emb     = (const float*)d_in[1];
    const float* W1      = (const float*)d_in[2];
    const float* b1      = (const float*)d_in[3];
    const float* W2      = (const float*)d_in[4];
    const float* b2      = (const float*)d_in[5];
    const float* gamma   = (const float*)d_in[6];
    const float* beta    = (const float*)d_in[7];

    const int E = in_sizes[0] / 2;
    const int N = in_sizes[1] / DIM;
    const int* src = ei;
    const int* dst = ei + E;
    const int nbuck = (N + NPB - 1) / NPB;          // 391 for N=100000

    // workspace carve-up (256B aligned) — ~93MB, below proven ~118MB budget
    char* w = (char*)d_ws;
    size_t off = 0;
    auto alloc = [&](size_t bytes) -> void* {
        off = (off + 255) & ~(size_t)255;
        void* p = w + off;
        off += bytes;
        return p;
    };
    int*      deg      = (int*)     alloc((size_t)N * 4);
    float*    dinv     = (float*)   alloc((size_t)N * 4);
    int*      rowstart = (int*)     alloc((size_t)(N + 1) * 4);
    int*      gcur     = (int*)     alloc((size_t)(nbuck + 1) * 4);
    int*      part     = (int*)     alloc(1024);
    int*      csr_col  = (int*)     alloc((size_t)E * 4);
    uint2*    stage    = (uint2*)   alloc((size_t)E * 8);
    float*    rs       = (float*)   alloc((size_t)N * 4);
    uint2*    agg2h    = (uint2*)   alloc((size_t)N * DIM * 2);   // fp16 [N,256]
    _Float16* WcTh     = (_Float16*)alloc((size_t)DIM * DIM * 2); // fp16 Wc^T
    float*    cvec     = (float*)   alloc(DIM * 4);
    float*    bnsum    = (float*)   alloc(2 * DIM * 4);   // sum | sumsq
    float*    bnscale  = (float*)   alloc(2 * DIM * 4);   // scale | shift

    // fp16 tables alias d_out (dead until the GEMM writes it):
    //   [0, N*DIM*2)        xh    = u-table of emb  (dinv-prescaled)
    //   [N*DIM*2, N*DIM*4)  agg1h = u2-table (pass-1 output)
    uint2* xh    = (uint2*)d_out;
    uint2* agg1h = (uint2*)((char*)d_out + (size_t)N * DIM * 2);
    float* out   = (float*)d_out;

    const int nb1024 = (N + 1023) / 1024;

    // 1. degree + dinv
    k_deg_init<<<(N + 255) / 256, 256, 0, stream>>>(deg, N);
    k_deg_count<<<2048, 256, 0, stream>>>(dst, deg, E);
    k_dinv<<<(N + 255) / 256, 256, 0, stream>>>(deg, dinv, N);

    // 2. u-table of emb (dinv-prescaled fp16)
    k_tohalf_u<<<2048, 256, 0, stream>>>((const float4*)emb, dinv, xh, N * DIM4);

    // 3. CSR build (bucketed two-pass fill)
    k_scan_partial<<<nb1024, 256, 0, stream>>>(deg, part, N);
    k_scan_offsets<<<1, 1, 0, stream>>>(part, rowstart, nb1024, N);
    k_scan_write<<<nb1024, 256, 0, stream>>>(deg, part, rowstart, N);
    k_bucket_init<<<(nbuck + 255) / 256, 256, 0, stream>>>(rowstart, gcur, N, nbuck);
    k_binfill<<<256, 256, 0, stream>>>(src, dst, gcur, stage, E, nbuck);
    k_csrbuild<<<nbuck, 256, 0, stream>>>(stage, rowstart, csr_col, N);

    // 3b. rs = A @ 1  (wave per node)
    k_rs<<<(N + 3) / 4, 256, 0, stream>>>(dinv, rowstart, csr_col, rs, N);

    // 4. pass 1: agg1h = fp16( dinv^2 * (sum u + u_self) )  == next u-table
    k_agg_u<<<(N + 3) / 4, 256, 0, stream>>>(xh, dinv, rowstart, csr_col, agg1h, N, 1);
    // 5. pass 2: agg2h = fp16( dinv * (sum u2 + u2_self) )  == y2 for GEMM
    k_agg_u<<<(N + 3) / 4, 256, 0, stream>>>(agg1h, dinv, rowstart, csr_col, agg2h, N, 0);

    // 6. weight collapse (fp16 transposed for MFMA B-operand)
    k_wct<<<DIM, DIM, 0, stream>>>(W1, W2, WcTh);
    k_cvec<<<1, DIM, 0, stream>>>(b1, W2, cvec);

    // 7. h2 = agg2 @ Wc + rs⊗cvec + b2  -> d_out (overwrites dead fp16 tables)
    dim3 ggrid((N + GBM - 1) / GBM, DIM / GBN);
    k_gemm_mfma<<<ggrid, 256, 0, stream>>>((const _Float16*)agg2h, WcTh, rs, cvec, b2, out, N);

    // 8. BatchNorm
    k_bnzero<<<1, 512, 0, stream>>>(bnsum);
    k_bnstats<<<512, 256, 0, stream>>>(out, bnsum, bnsum + DIM, N);
    k_bnfinal<<<1, DIM, 0, stream>>>(bnsum, bnsum + DIM, gamma, beta,
                                     bnscale, bnscale + DIM, N);
    k_bnnorm<<<2048, 256, 0, stream>>>((float4*)out, (const float4*)bnscale,
                                       (const float4*)(bnscale + DIM), N * DIM4);
}